// Round 2
// baseline (2118.574 us; speedup 1.0000x reference)
//
#include <hip/hip_runtime.h>
#include <hip/hip_bf16.h>

// CustomTransformer: 4-layer encoder (d=512, ff=64) + fc(512->128) + 64-step
// greedy-style decoder scan with ONE decoder layer (d=128, ff=16).
// Key algebraic reduction: at scan step t only output row t is consumed, and
// zero rows of tgt contribute identical K/V (= bias) -> incremental decode
// with K/V cache + multiplicity-(65-t) "zero-row" logit is EXACT.

typedef __attribute__((ext_vector_type(8))) short bf16x8;
typedef __attribute__((ext_vector_type(4))) float f32x4;
typedef __attribute__((ext_vector_type(4))) unsigned int u32x4;

#define LN_EPS 1e-5f

__device__ __forceinline__ unsigned short f2bfbits(float f){
  union { __hip_bfloat16 h; unsigned short u; } cv;
  cv.h = __float2bfloat16(f);   // RNE
  return cv.u;
}
__device__ __forceinline__ float bf2f(unsigned short s){
  return __uint_as_float(((unsigned)s) << 16);
}

// ---------------------------------------------------------------------------
// Encoder GEMM: C[M,N] = A[M,K] @ W[N,K]^T (+bias)(+resid)(optional relu)
// bf16 MFMA 16x16x32, inline f32->bf16 conversion (v_cvt_pk expected).
// Block 256 = 4 waves in 2x2; block tile 64x64; wave tile 32x32 (2x2 frags).
// ---------------------------------------------------------------------------
__device__ __forceinline__ bf16x8 load_frag_f32(const float* __restrict__ p){
  f32x4 u = *(const f32x4*)p;
  f32x4 v = *(const f32x4*)(p + 4);
  bf16x8 r;
  r[0] = (short)f2bfbits(u.x); r[1] = (short)f2bfbits(u.y);
  r[2] = (short)f2bfbits(u.z); r[3] = (short)f2bfbits(u.w);
  r[4] = (short)f2bfbits(v.x); r[5] = (short)f2bfbits(v.y);
  r[6] = (short)f2bfbits(v.z); r[7] = (short)f2bfbits(v.w);
  return r;
}

__global__ void __launch_bounds__(256) gemm_kernel(
    const float* __restrict__ A, const float* __restrict__ W,
    const float* __restrict__ bias, const float* __restrict__ resid,
    float* __restrict__ C, int M, int N, int K, int relu)
{
  const int tid  = threadIdx.x;
  const int lane = tid & 63;
  const int wid  = tid >> 6;
  const int rowBase = blockIdx.x * 64 + (wid >> 1) * 32;
  const int colBase = blockIdx.y * 64 + (wid & 1) * 32;
  const int r16 = lane & 15;
  const int kg  = lane >> 4;           // 0..3

  f32x4 zz = {0.f, 0.f, 0.f, 0.f};
  f32x4 acc[2][2];
  acc[0][0] = zz; acc[0][1] = zz; acc[1][0] = zz; acc[1][1] = zz;

  for (int k0 = 0; k0 < K; k0 += 32){
    const int ks = k0 + kg * 8;
    bf16x8 af[2], bfr[2];
    #pragma unroll
    for (int mt = 0; mt < 2; ++mt)
      af[mt] = load_frag_f32(A + (size_t)(rowBase + mt*16 + r16) * K + ks);
    #pragma unroll
    for (int nt = 0; nt < 2; ++nt)
      bfr[nt] = load_frag_f32(W + (size_t)(colBase + nt*16 + r16) * K + ks);
    #pragma unroll
    for (int mt = 0; mt < 2; ++mt)
      #pragma unroll
      for (int nt = 0; nt < 2; ++nt)
        acc[mt][nt] = __builtin_amdgcn_mfma_f32_16x16x32_bf16(af[mt], bfr[nt], acc[mt][nt], 0, 0, 0);
  }

  #pragma unroll
  for (int mt = 0; mt < 2; ++mt)
  #pragma unroll
  for (int nt = 0; nt < 2; ++nt)
  #pragma unroll
  for (int i = 0; i < 4; ++i){
    int row = rowBase + mt*16 + (lane >> 4) * 4 + i;   // C/D: row=(lane>>4)*4+i
    int col = colBase + nt*16 + r16;                   //      col=lane&15
    float v = acc[mt][nt][i];
    if (bias)  v += bias[col];
    if (resid) v += resid[(size_t)row * N + col];
    if (relu)  v = fmaxf(v, 0.f);
    C[(size_t)row * N + col] = v;
  }
}

// ---------------------------------------------------------------------------
// Encoder attention: one block per (batch, head). dh=64, S=64, scale=1/8.
// ---------------------------------------------------------------------------
#define APAD 68
__global__ void __launch_bounds__(256) enc_attn_kernel(
    const float* __restrict__ QKV, float* __restrict__ O)
{
  __shared__ __attribute__((aligned(16))) float Qs[64][APAD];
  __shared__ __attribute__((aligned(16))) float Ks[64][APAD];
  __shared__ __attribute__((aligned(16))) float Vs[64][APAD];
  __shared__ __attribute__((aligned(16))) float Ss[64][APAD];
  const int b = blockIdx.x, h = blockIdx.y;
  const int tid = threadIdx.x;
  const float* base = QKV + (size_t)b * 64 * 1536 + h * 64;
  for (int idx = tid; idx < 64 * 16; idx += 256){
    int t = idx >> 4, c4 = (idx & 15) << 2;
    const float* rp = base + (size_t)t * 1536 + c4;
    *(f32x4*)&Qs[t][c4] = *(const f32x4*)rp;
    *(f32x4*)&Ks[t][c4] = *(const f32x4*)(rp + 512);
    *(f32x4*)&Vs[t][c4] = *(const f32x4*)(rp + 1024);
  }
  __syncthreads();
  const int r = tid >> 2, cg = tid & 3;   // 4 lanes per row, 16 cols each
  float qr[64];
  #pragma unroll
  for (int k4 = 0; k4 < 16; ++k4) *(f32x4*)&qr[k4*4] = *(const f32x4*)&Qs[r][k4*4];
  float sv[16];
  #pragma unroll
  for (int i = 0; i < 16; ++i){
    int c = cg * 16 + i;
    float acc = 0.f;
    #pragma unroll
    for (int k4 = 0; k4 < 16; ++k4){
      f32x4 kv = *(const f32x4*)&Ks[c][k4*4];
      acc += qr[k4*4+0]*kv.x + qr[k4*4+1]*kv.y + qr[k4*4+2]*kv.z + qr[k4*4+3]*kv.w;
    }
    sv[i] = acc * 0.125f;
  }
  float mx = -1e30f;
  #pragma unroll
  for (int i = 0; i < 16; ++i) mx = fmaxf(mx, sv[i]);
  mx = fmaxf(mx, __shfl_xor(mx, 1));
  mx = fmaxf(mx, __shfl_xor(mx, 2));
  float sum = 0.f;
  #pragma unroll
  for (int i = 0; i < 16; ++i){ sv[i] = __expf(sv[i] - mx); sum += sv[i]; }
  sum += __shfl_xor(sum, 1);
  sum += __shfl_xor(sum, 2);
  float inv = 1.f / sum;
  #pragma unroll
  for (int i = 0; i < 16; ++i) Ss[r][cg*16 + i] = sv[i] * inv;
  __syncthreads();
  float ar[64];
  #pragma unroll
  for (int k4 = 0; k4 < 16; ++k4) *(f32x4*)&ar[k4*4] = *(const f32x4*)&Ss[r][k4*4];
  f32x4 zz = {0.f,0.f,0.f,0.f};
  f32x4 o4[4]; o4[0]=zz; o4[1]=zz; o4[2]=zz; o4[3]=zz;
  for (int k = 0; k < 64; ++k){
    float s = ar[k];
    #pragma unroll
    for (int q = 0; q < 4; ++q){
      f32x4 v = *(const f32x4*)&Vs[k][cg*16 + q*4];
      o4[q] += v * s;
    }
  }
  float* op = O + (size_t)(b * 64 + r) * 512 + h * 64 + cg * 16;
  #pragma unroll
  for (int q = 0; q < 4; ++q) *(f32x4*)(op + q*4) = o4[q];
}

// ---------------------------------------------------------------------------
// LayerNorm over D=512, one wave per row (4 rows / block).
// ---------------------------------------------------------------------------
__global__ void __launch_bounds__(256) ln512_kernel(const float* __restrict__ R,
    const float* __restrict__ g, const float* __restrict__ bb, float* __restrict__ X)
{
  const int row  = blockIdx.x * 4 + (threadIdx.x >> 6);
  const int lane = threadIdx.x & 63;
  const float* p = R + (size_t)row * 512 + lane * 8;
  f32x4 u = *(const f32x4*)p;
  f32x4 v = *(const f32x4*)(p + 4);
  float s  = u.x+u.y+u.z+u.w + v.x+v.y+v.z+v.w;
  float sq = u.x*u.x+u.y*u.y+u.z*u.z+u.w*u.w + v.x*v.x+v.y*v.y+v.z*v.z+v.w*v.w;
  #pragma unroll
  for (int off = 1; off < 64; off <<= 1){
    s  += __shfl_xor(s, off);
    sq += __shfl_xor(sq, off);
  }
  float mu   = s  * (1.f/512.f);
  float var  = sq * (1.f/512.f) - mu*mu;
  float rstd = rsqrtf(var + LN_EPS);
  const float* gp = g  + lane * 8;
  const float* bp = bb + lane * 8;
  f32x4 g0 = *(const f32x4*)gp,     g1 = *(const f32x4*)(gp+4);
  f32x4 b0 = *(const f32x4*)bp,     b1 = *(const f32x4*)(bp+4);
  f32x4 o0, o1;
  o0.x = (u.x-mu)*rstd*g0.x + b0.x;  o0.y = (u.y-mu)*rstd*g0.y + b0.y;
  o0.z = (u.z-mu)*rstd*g0.z + b0.z;  o0.w = (u.w-mu)*rstd*g0.w + b0.w;
  o1.x = (v.x-mu)*rstd*g1.x + b1.x;  o1.y = (v.y-mu)*rstd*g1.y + b1.y;
  o1.z = (v.z-mu)*rstd*g1.z + b1.z;  o1.w = (v.w-mu)*rstd*g1.w + b1.w;
  float* xp = X + (size_t)row * 512 + lane * 8;
  *(f32x4*)xp       = o0;
  *(f32x4*)(xp + 4) = o1;
}

// ---------------------------------------------------------------------------
// Decode helpers
// ---------------------------------------------------------------------------
// dot(len=128) of XOR-swizzled LDS bf16 row r with LDS fp32 vector x.
// Storage swizzle: element (r,c) at r*128 + ((c>>3)^(r&7))<<3 + (c&7)
// (breaks the stride-256B full-wave bank conflict; 16B chunks stay contiguous)
__device__ __forceinline__ float dot128_swz(const unsigned short* __restrict__ w,
                                            int r, const float* __restrict__ x){
  const unsigned short* row = w + (r << 7);
  const int rs = r & 7;
  float acc = 0.f;
  #pragma unroll
  for (int cb = 0; cb < 16; ++cb){
    int off = ((cb ^ rs) << 3);
    u32x4 u = *(const u32x4*)(row + off);
    const float* xx = x + (cb << 3);
    acc += bf2f((unsigned short)(u[0] & 0xffffu)) * xx[0];
    acc += bf2f((unsigned short)(u[0] >> 16))     * xx[1];
    acc += bf2f((unsigned short)(u[1] & 0xffffu)) * xx[2];
    acc += bf2f((unsigned short)(u[1] >> 16))     * xx[3];
    acc += bf2f((unsigned short)(u[2] & 0xffffu)) * xx[4];
    acc += bf2f((unsigned short)(u[2] >> 16))     * xx[5];
    acc += bf2f((unsigned short)(u[3] & 0xffffu)) * xx[6];
    acc += bf2f((unsigned short)(u[3] >> 16))     * xx[7];
  }
  return acc;
}

__device__ __forceinline__ float dot16b(const unsigned short* __restrict__ w,
                                        int r, const float* __restrict__ x){
  const unsigned short* row = w + r * 16;
  float acc = 0.f;
  #pragma unroll
  for (int cb = 0; cb < 2; ++cb){
    u32x4 u = *(const u32x4*)(row + cb * 8);
    const float* xx = x + cb * 8;
    acc += bf2f((unsigned short)(u[0] & 0xffffu)) * xx[0];
    acc += bf2f((unsigned short)(u[0] >> 16))     * xx[1];
    acc += bf2f((unsigned short)(u[1] & 0xffffu)) * xx[2];
    acc += bf2f((unsigned short)(u[1] >> 16))     * xx[3];
    acc += bf2f((unsigned short)(u[2] & 0xffffu)) * xx[4];
    acc += bf2f((unsigned short)(u[2] >> 16))     * xx[5];
    acc += bf2f((unsigned short)(u[3] & 0xffffu)) * xx[6];
    acc += bf2f((unsigned short)(u[3] >> 16))     * xx[7];
  }
  return acc;
}

// dot(len=128) of a GLOBAL fp32 weight row with an LDS fp32 vector.
__device__ __forceinline__ float dotg128(const float* __restrict__ w,
                                         const float* __restrict__ x){
  float acc = 0.f;
  #pragma unroll
  for (int q = 0; q < 32; ++q){
    f32x4 a = *(const f32x4*)(w + q * 4);
    acc += a.x*x[q*4+0] + a.y*x[q*4+1] + a.z*x[q*4+2] + a.w*x[q*4+3];
  }
  return acc;
}

// LayerNorm over 128 LDS values (all 256 threads must call: contains barriers)
__device__ __forceinline__ void ln128(const float* __restrict__ in, float* __restrict__ out,
    const float* __restrict__ g, const float* __restrict__ bb,
    float* __restrict__ mustd, int tid)
{
  __syncthreads();
  if (tid < 64){
    float a = in[tid], c = in[tid + 64];
    float s = a + c, sq = a*a + c*c;
    #pragma unroll
    for (int off = 1; off < 64; off <<= 1){
      s  += __shfl_xor(s, off);
      sq += __shfl_xor(sq, off);
    }
    if (tid == 0){
      float mu  = s  * (1.f/128.f);
      float var = sq * (1.f/128.f) - mu*mu;
      mustd[0] = mu;
      mustd[1] = rsqrtf(var + LN_EPS);
    }
  }
  __syncthreads();
  if (tid < 128) out[tid] = (in[tid] - mustd[0]) * mustd[1] * g[tid] + bb[tid];
}

// ---------------------------------------------------------------------------
// Decoder: one workgroup per batch, 64 serial steps with incremental KV cache.
// Zero-input tgt rows contribute key/value = bias with multiplicity (65 - t).
// ---------------------------------------------------------------------------
__global__ void __launch_bounds__(256) decode_kernel(
    const float* __restrict__ MEM,
    const float* __restrict__ saqkv_w, const float* __restrict__ saqkv_b,
    const float* __restrict__ saout_w, const float* __restrict__ saout_b,
    const float* __restrict__ caqkv_w, const float* __restrict__ caqkv_b,
    const float* __restrict__ caout_w, const float* __restrict__ caout_b,
    const float* __restrict__ f1w, const float* __restrict__ f1b,
    const float* __restrict__ f2w, const float* __restrict__ f2b,
    const float* __restrict__ g1, const float* __restrict__ b1,
    const float* __restrict__ g2, const float* __restrict__ b2,
    const float* __restrict__ g3, const float* __restrict__ b3,
    float* __restrict__ Kc, float* __restrict__ Vc,
    float* __restrict__ Ksa, float* __restrict__ Vsa,
    float* __restrict__ Out)
{
  // bf16 weights resident in LDS for the whole 64-step loop (~139 KB)
  __shared__ __attribute__((aligned(16))) unsigned short wsaqkv[384*128];
  __shared__ __attribute__((aligned(16))) unsigned short wsaout[128*128];
  __shared__ __attribute__((aligned(16))) unsigned short wff1[16*128];
  __shared__ __attribute__((aligned(16))) unsigned short wff2[128*16];
  __shared__ __attribute__((aligned(16))) float xcur[128], x1[128], x2b[128];
  __shared__ __attribute__((aligned(16))) float qbuf[128], obuf[128], rtmp[128];
  __shared__ float hbuf[16];
  __shared__ float scores[8][64];
  __shared__ float s0h[8], w0h[8], Dh[8];
  __shared__ float mustd[2];
  __shared__ __attribute__((aligned(16))) float k0v[128], v0v[128];
  __shared__ float bsaq[384];
  __shared__ float bsao[128], bcaq[128], bcao[128], bft2[128];
  __shared__ float bft1[16];
  __shared__ float lg1[128], lb1[128], lg2[128], lb2[128], lg3[128], lb3[128];

  const int b   = blockIdx.x;
  const int tid = threadIdx.x;

  // --- preamble 1: cross-attn K/V over mem (fp32 exact, weight row in regs) ---
  {
    float* memtmp = (float*)wsaqkv;     // temp: 64x128 floats (region reused later)
    for (int i = tid; i < 8192; i += 256) memtmp[i] = MEM[(size_t)b*8192 + i];
    __syncthreads();
    const float* wr = caqkv_w + (size_t)(128 + tid) * 128;   // rows 128..383: Wk|Wv
    f32x4 wreg[32];
    #pragma unroll
    for (int q = 0; q < 32; ++q) wreg[q] = *(const f32x4*)(wr + q*4);
    const float bias = caqkv_b[128 + tid];
    float* dst = (tid < 128) ? (Kc + (size_t)b*8192 + tid)
                             : (Vc + (size_t)b*8192 + (tid - 128));
    for (int j = 0; j < 64; ++j){
      const f32x4* mrow = (const f32x4*)(memtmp + j*128);
      float acc = bias;
      #pragma unroll
      for (int q = 0; q < 32; ++q){
        f32x4 m = mrow[q];
        f32x4 w = wreg[q];
        acc += w.x*m.x + w.y*m.y + w.z*m.z + w.w*m.w;
      }
      dst[(size_t)j * 128] = acc;
    }
    __syncthreads();
  }

  // --- preamble 2: params + bf16 LDS weights (XOR swizzled) ---
  for (int i = tid; i < 384; i += 256) bsaq[i] = saqkv_b[i];
  for (int i = tid; i < 128; i += 256){
    bsao[i] = saout_b[i]; bcaq[i] = caqkv_b[i]; bcao[i] = caout_b[i]; bft2[i] = f2b[i];
    lg1[i] = g1[i]; lb1[i] = b1[i]; lg2[i] = g2[i]; lb2[i] = b2[i]; lg3[i] = g3[i]; lb3[i] = b3[i];
    k0v[i] = saqkv_b[128 + i];    // zero-row key   = Wk@0 + bk
    v0v[i] = saqkv_b[256 + i];    // zero-row value = Wv@0 + bv
    xcur[i] = 0.f;                // tgt row 0 is zero
  }
  if (tid < 16) bft1[tid] = f1b[tid];
  for (int e = tid; e < 384*128; e += 256){
    int r = e >> 7, c = e & 127;
    wsaqkv[(r << 7) + (((c >> 3) ^ (r & 7)) << 3) + (c & 7)] = f2bfbits(saqkv_w[e]);
  }
  for (int e = tid; e < 128*128; e += 256){
    int r = e >> 7, c = e & 127;
    wsaout[(r << 7) + (((c >> 3) ^ (r & 7)) << 3) + (c & 7)] = f2bfbits(saout_w[e]);
  }
  for (int e = tid; e < 16*128; e += 256){
    int r = e >> 7, c = e & 127;
    wff1[(r << 7) + (((c >> 3) ^ (r & 7)) << 3) + (c & 7)] = f2bfbits(f1w[e]);
  }
  for (int e = tid; e < 128*16; e += 256) wff2[e] = f2bfbits(f2w[e]);
  __syncthreads();

  for (int t = 0; t < 64; ++t){
    // A: q for current row; if t>0 also append K/V of newly-filled row t
    const int nout = (t > 0) ? 384 : 128;
    for (int o = tid; o < nout; o += 256){
      float acc = dot128_swz(wsaqkv, o, xcur) + bsaq[o];
      if (o < 128)       qbuf[o] = acc;
      else if (o < 256)  Ksa[((size_t)(b*64 + t))*128 + (o - 128)] = acc;
      else               Vsa[((size_t)(b*64 + t))*128 + (o - 256)] = acc;
    }
    __syncthreads();
    // C: SA scores for filled rows j=1..t, plus zero-row logit per head
    for (int p = tid; p < 8*t; p += 256){
      int h = p & 7, j = 1 + (p >> 3);
      const float* kr = Ksa + ((size_t)(b*64 + j))*128 + h*16;
      const float* qh = qbuf + h*16;
      float acc = 0.f;
      #pragma unroll
      for (int d = 0; d < 16; ++d) acc += qh[d]*kr[d];
      scores[h][j] = acc * 0.25f;
    }
    if (tid < 8){
      const float* qh = qbuf + tid*16;
      const float* kh = k0v  + tid*16;
      float acc = 0.f;
      #pragma unroll
      for (int d = 0; d < 16; ++d) acc += qh[d]*kh[d];
      s0h[tid] = acc * 0.25f;
    }
    __syncthreads();
    // D: SA softmax, zero-row logit with multiplicity (65 - t)
    if (tid < 64){
      int h = tid >> 3, sub = tid & 7;
      float mx = (sub == 0) ? s0h[h] : -1e30f;
      for (int j = 1 + sub; j <= t; j += 8) mx = fmaxf(mx, scores[h][j]);
      mx = fmaxf(mx, __shfl_xor(mx, 1));
      mx = fmaxf(mx, __shfl_xor(mx, 2));
      mx = fmaxf(mx, __shfl_xor(mx, 4));
      float sum = 0.f;
      for (int j = 1 + sub; j <= t; j += 8){
        float e = __expf(scores[h][j] - mx);
        scores[h][j] = e;
        sum += e;
      }
      if (sub == 0){
        float w0 = (float)(65 - t) * __expf(s0h[h] - mx);
        w0h[h] = w0;
        sum += w0;
      }
      sum += __shfl_xor(sum, 1);
      sum += __shfl_xor(sum, 2);
      sum += __shfl_xor(sum, 4);
      if (sub == 0) Dh[h] = sum;
    }
    __syncthreads();
    // E: SA weighted values
    if (tid < 128){
      int h = tid >> 4;
      float acc = w0h[h] * v0v[tid];
      for (int j = 1; j <= t; ++j)
        acc += scores[h][j] * Vsa[((size_t)(b*64 + j))*128 + tid];
      obuf[tid] = acc / Dh[h];
    }
    __syncthreads();
    // F: SA out-proj + residual -> LN1 -> x1
    if (tid < 128) rtmp[tid] = dot128_swz(wsaout, tid, obuf) + bsao[tid] + xcur[tid];
    ln128(rtmp, x1, lg1, lb1, mustd, tid);
    __syncthreads();
    // G: CA q (fp32 weights streamed from L2)
    if (tid < 128) qbuf[tid] = dotg128(caqkv_w + (size_t)tid*128, x1) + bcaq[tid];
    __syncthreads();
    // H: CA scores over 64 mem keys
    for (int p = tid; p < 512; p += 256){
      int h = p & 7, j = p >> 3;
      const float* kr = Kc + ((size_t)(b*64 + j))*128 + h*16;
      const float* qh = qbuf + h*16;
      float acc = 0.f;
      #pragma unroll
      for (int d = 0; d < 16; ++d) acc += qh[d]*kr[d];
      scores[h][j] = acc * 0.25f;
    }
    __syncthreads();
    // I: CA softmax
    if (tid < 64){
      int h = tid >> 3, sub = tid & 7;
      float mx = -1e30f;
      #pragma unroll
      for (int i = 0; i < 8; ++i) mx = fmaxf(mx, scores[h][sub*8 + i]);
      mx = fmaxf(mx, __shfl_xor(mx, 1));
      mx = fmaxf(mx, __shfl_xor(mx, 2));
      mx = fmaxf(mx, __shfl_xor(mx, 4));
      float sum = 0.f;
      #pragma unroll
      for (int i = 0; i < 8; ++i){
        float e = __expf(scores[h][sub*8 + i] - mx);
        scores[h][sub*8 + i] = e;
        sum += e;
      }
      sum += __shfl_xor(sum, 1);
      sum += __shfl_xor(sum, 2);
      sum += __shfl_xor(sum, 4);
      if (sub == 0) Dh[h] = sum;
    }
    __syncthreads();
    // J: CA weighted values
    if (tid < 128){
      int h = tid >> 4;
      float acc = 0.f;
      for (int j = 0; j < 64; ++j)
        acc += scores[h][j] * Vc[((size_t)(b*64 + j))*128 + tid];
      obuf[tid] = acc / Dh[h];
    }
    __syncthreads();
    // K: CA out-proj + residual -> LN2 -> x2
    if (tid < 128) rtmp[tid] = dotg128(caout_w + (size_t)tid*128, obuf) + bcao[tid] + x1[tid];
    ln128(rtmp, x2b, lg2, lb2, mustd, tid);
    __syncthreads();
    // L: FFN (16 hidden) -> LN3 -> new xcur
    if (tid < 16) hbuf[tid] = fmaxf(dot128_swz(wff1, tid, x2b) + bft1[tid], 0.f);
    __syncthreads();
    if (tid < 128) rtmp[tid] = dot16b(wff2, tid, hbuf) + bft2[tid] + x2b[tid];
    ln128(rtmp, xcur, lg3, lb3, mustd, tid);
    __syncthreads();
    if (tid < 128) Out[((size_t)(b*64 + t))*128 + tid] = xcur[tid];
    __syncthreads();
  }
}

// ---------------------------------------------------------------------------
extern "C" void kernel_launch(void* const* d_in, const int* in_sizes, int n_in,
                              void* d_out, int out_size, void* d_ws, size_t ws_size,
                              hipStream_t stream)
{
  (void)in_sizes; (void)n_in; (void)out_size; (void)ws_size;
  const float* src   = (const float*)d_in[0];
  const float* eqkvw = (const float*)d_in[1];
  const float* eqkvb = (const float*)d_in[2];
  const float* eow   = (const float*)d_in[3];
  const float* eob   = (const float*)d_in[4];
  const float* ef1w  = (const float*)d_in[5];
  const float* ef1b  = (const float*)d_in[6];
  const float* ef2w  = (const float*)d_in[7];
  const float* ef2b  = (const float*)d_in[8];
  const float* eg1   = (const float*)d_in[9];
  const float* eb1   = (const float*)d_in[10];
  const float* eg2   = (const float*)d_in[11];
  const float* eb2   = (const float*)d_in[12];
  const float* fcw   = (const float*)d_in[13];
  const float* fcb   = (const float*)d_in[14];
  const float* dsaqw = (const float*)d_in[15];
  const float* dsaqb = (const float*)d_in[16];
  const float* dsaow = (const float*)d_in[17];
  const float* dsaob = (const float*)d_in[18];
  const float* dcaqw = (const float*)d_in[19];
  const float* dcaqb = (const float*)d_in[20];
  const float* dcaow = (const float*)d_in[21];
  const float* dcaob = (const float*)d_in[22];
  const float* df1w  = (const float*)d_in[23];
  const float* df1b  = (const float*)d_in[24];
  const float* df2w  = (const float*)d_in[25];
  const float* df2b  = (const float*)d_in[26];
  const float* dg1   = (const float*)d_in[27];
  const float* db1   = (const float*)d_in[28];
  const float* dg2   = (const float*)d_in[29];
  const float* db2   = (const float*)d_in[30];
  const float* dg3   = (const float*)d_in[31];
  const float* db3   = (const float*)d_in[32];

  // ws layout (floats). Regions reuse dead buffers; max = 6,291,456 fl = 25.2 MB.
  float* ws   = (float*)d_ws;
  float* QKV  = ws;                 // [2048,1536]  (encoder-phase)
  float* Rb   = ws;                 // [2048,512]   overlays dead QKV
  float* Hb   = ws + 1048576;       // [2048,64]    overlays dead QKV
  float* Ob   = ws + 3145728;       // [2048,512]
  float* XA   = ws + 4194304;       // [2048,512]
  float* XB   = ws + 5242880;       // [2048,512]
  float* MEMb = XB;                 // [2048,128]   overlays dead XB (decode phase)
  float* Kc   = Ob;                 // [32,64,128]  overlays dead Ob
  float* Vc   = Ob + 262144;
  float* Ksa  = Ob + 524288;
  float* Vsa  = Ob + 786432;

  const float* Xin = src;
  for (int l = 0; l < 4; ++l){
    gemm_kernel<<<dim3(32,24),256,0,stream>>>(Xin, eqkvw + (size_t)l*1536*512, eqkvb + l*1536, nullptr, QKV, 2048, 1536, 512, 0);
    enc_attn_kernel<<<dim3(32,8),256,0,stream>>>(QKV, Ob);
    gemm_kernel<<<dim3(32,8),256,0,stream>>>(Ob, eow + (size_t)l*512*512, eob + l*512, Xin, Rb, 2048, 512, 512, 0);
    ln512_kernel<<<dim3(512),256,0,stream>>>(Rb, eg1 + l*512, eb1 + l*512, XB);
    gemm_kernel<<<dim3(32,1),256,0,stream>>>(XB, ef1w + (size_t)l*64*512, ef1b + l*64, nullptr, Hb, 2048, 64, 512, 1);
    gemm_kernel<<<dim3(32,8),256,0,stream>>>(Hb, ef2w + (size_t)l*512*64, ef2b + l*512, XB, Rb, 2048, 512, 64, 0);
    ln512_kernel<<<dim3(512),256,0,stream>>>(Rb, eg2 + l*512, eb2 + l*512, XA);
    Xin = XA;
  }
  gemm_kernel<<<dim3(32,2),256,0,stream>>>(XA, fcw, fcb, nullptr, MEMb, 2048, 128, 512, 0);
  decode_kernel<<<dim3(32),256,0,stream>>>(MEMb,
      dsaqw, dsaqb, dsaow, dsaob, dcaqw, dcaqb, dcaow, dcaob,
      df1w, df1b, df2w, df2b, dg1, db1, dg2, db2, dg3, db3,
      Kc, Vc, Ksa, Vsa, (float*)d_out);
}

// Round 10
// 1877.133 us; speedup vs baseline: 1.1286x; 1.1286x over previous
//
#include <hip/hip_runtime.h>
#include <hip/hip_bf16.h>

// CustomTransformer: 4-layer encoder (d=512, ff=64) + fc(512->128) + 64-step
// decoder scan. Decoder runs as ONE WAVE per batch: all matvecs/attention via
// MFMA 16x16x32 bf16, K/V caches in LDS bf16, weights streamed from L2 as
// pre-converted bf16. Zero-row reduction: at step t, the 65-t zero rows of tgt
// share K/V = bias -> slot j=0 holds the zero-row with multiplicity (65-t).

typedef __attribute__((ext_vector_type(8))) short bf16x8;
typedef __attribute__((ext_vector_type(4))) float f32x4;
typedef __attribute__((ext_vector_type(4))) unsigned int u32x4;
typedef unsigned short ushort_t;
typedef unsigned int uint_t;

#define LN_EPS 1e-5f
#define KC_STRIDE 136   // bf16 elems; 272B = 68 words == 4 mod 32 -> uniform banks
#define VT_STRIDE 72    // bf16 elems; 144B = 36 words == 4 mod 32 -> uniform banks
#define SC_STRIDE 72    // f32 elems

__device__ __forceinline__ ushort_t f2bfbits(float f){
  union { __hip_bfloat16 h; ushort_t u; } cv;
  cv.h = __float2bfloat16(f);   // RNE
  return cv.u;
}
__device__ __forceinline__ uint_t pack2(float a, float b){
  return (uint_t)f2bfbits(a) | ((uint_t)f2bfbits(b) << 16);
}
__device__ __forceinline__ bf16x8 pack8(f32x4 u, f32x4 v){
  bf16x8 r;
  r[0]=(short)f2bfbits(u.x); r[1]=(short)f2bfbits(u.y);
  r[2]=(short)f2bfbits(u.z); r[3]=(short)f2bfbits(u.w);
  r[4]=(short)f2bfbits(v.x); r[5]=(short)f2bfbits(v.y);
  r[6]=(short)f2bfbits(v.z); r[7]=(short)f2bfbits(v.w);
  return r;
}

// ---------------------------------------------------------------------------
// Batched f32 -> bf16 conversion (up to 10 tensors, selected by blockIdx.y)
// ---------------------------------------------------------------------------
__global__ void __launch_bounds__(256) cvt10(
    const float* s0, ushort_t* d0, int n0,
    const float* s1, ushort_t* d1, int n1,
    const float* s2, ushort_t* d2, int n2,
    const float* s3, ushort_t* d3, int n3,
    const float* s4, ushort_t* d4, int n4,
    const float* s5, ushort_t* d5, int n5,
    const float* s6, ushort_t* d6, int n6,
    const float* s7, ushort_t* d7, int n7,
    const float* s8, ushort_t* d8, int n8,
    const float* s9, ushort_t* d9, int n9)
{
  const float* s; ushort_t* d; int n;
  switch (blockIdx.y){
    case 0: s=s0; d=d0; n=n0; break;
    case 1: s=s1; d=d1; n=n1; break;
    case 2: s=s2; d=d2; n=n2; break;
    case 3: s=s3; d=d3; n=n3; break;
    case 4: s=s4; d=d4; n=n4; break;
    case 5: s=s5; d=d5; n=n5; break;
    case 6: s=s6; d=d6; n=n6; break;
    case 7: s=s7; d=d7; n=n7; break;
    case 8: s=s8; d=d8; n=n8; break;
    default: s=s9; d=d9; n=n9; break;
  }
  for (int i = (blockIdx.x*256 + threadIdx.x)*8; i < n; i += gridDim.x*256*8){
    f32x4 u = *(const f32x4*)(s + i);
    f32x4 v = *(const f32x4*)(s + i + 4);
    u32x4 w;
    w[0]=pack2(u.x,u.y); w[1]=pack2(u.z,u.w); w[2]=pack2(v.x,v.y); w[3]=pack2(v.z,v.w);
    *(u32x4*)(d + i) = w;
  }
}

// ---------------------------------------------------------------------------
// Encoder GEMM: C[M,N] = A[M,K] @ W[N,K]^T (+bias)(+resid f32)(relu)
// A,W bf16; out -> C (f32) and/or Cb (bf16). Pure b128-load + MFMA inner loop.
// ---------------------------------------------------------------------------
__global__ void __launch_bounds__(256) gemm_bf16(
    const ushort_t* __restrict__ A, const ushort_t* __restrict__ W,
    const float* __restrict__ bias, const float* __restrict__ resid,
    float* __restrict__ C, ushort_t* __restrict__ Cb,
    int M, int N, int K, int relu)
{
  const int tid  = threadIdx.x;
  const int lane = tid & 63;
  const int wid  = tid >> 6;
  const int rowBase = blockIdx.x * 64 + (wid >> 1) * 32;
  const int colBase = blockIdx.y * 64 + (wid & 1) * 32;
  const int r16 = lane & 15;
  const int kg  = lane >> 4;

  f32x4 zz = {0.f,0.f,0.f,0.f};
  f32x4 acc[2][2];
  acc[0][0]=zz; acc[0][1]=zz; acc[1][0]=zz; acc[1][1]=zz;

  const ushort_t* Ap = A + (size_t)(rowBase + r16) * K + kg*8;
  const ushort_t* Wp = W + (size_t)(colBase + r16) * K + kg*8;
  #pragma unroll 4
  for (int k0 = 0; k0 < K; k0 += 32){
    bf16x8 af0 = *(const bf16x8*)(Ap + k0);
    bf16x8 af1 = *(const bf16x8*)(Ap + (size_t)16*K + k0);
    bf16x8 bf0 = *(const bf16x8*)(Wp + k0);
    bf16x8 bf1 = *(const bf16x8*)(Wp + (size_t)16*K + k0);
    acc[0][0] = __builtin_amdgcn_mfma_f32_16x16x32_bf16(af0, bf0, acc[0][0], 0,0,0);
    acc[0][1] = __builtin_amdgcn_mfma_f32_16x16x32_bf16(af0, bf1, acc[0][1], 0,0,0);
    acc[1][0] = __builtin_amdgcn_mfma_f32_16x16x32_bf16(af1, bf0, acc[1][0], 0,0,0);
    acc[1][1] = __builtin_amdgcn_mfma_f32_16x16x32_bf16(af1, bf1, acc[1][1], 0,0,0);
  }

  #pragma unroll
  for (int mt = 0; mt < 2; ++mt)
  #pragma unroll
  for (int nt = 0; nt < 2; ++nt)
  #pragma unroll
  for (int i = 0; i < 4; ++i){
    int row = rowBase + mt*16 + kg*4 + i;   // C/D: row=(lane>>4)*4+i
    int col = colBase + nt*16 + r16;        //      col=lane&15
    float v = acc[mt][nt][i] + bias[col];
    if (resid) v += resid[(size_t)row * N + col];
    if (relu)  v = fmaxf(v, 0.f);
    if (C)  C[(size_t)row * N + col] = v;
    if (Cb) Cb[(size_t)row * N + col] = f2bfbits(v);
  }
}

// ---------------------------------------------------------------------------
// Encoder attention: one block per (batch, head). dh=64, S=64, scale=1/8.
// bf16 in (QKVb), bf16 out (Ob); fp32 compute.
// ---------------------------------------------------------------------------
#define APAD 68
__global__ void __launch_bounds__(256) enc_attn_kernel(
    const ushort_t* __restrict__ QKVb, ushort_t* __restrict__ Ob)
{
  __shared__ __attribute__((aligned(16))) float Qs[64][APAD];
  __shared__ __attribute__((aligned(16))) float Ks[64][APAD];
  __shared__ __attribute__((aligned(16))) float Vs[64][APAD];
  __shared__ __attribute__((aligned(16))) float Ss[64][APAD];
  const int b = blockIdx.x, h = blockIdx.y;
  const int tid = threadIdx.x;
  const ushort_t* base = QKVb + (size_t)b * 64 * 1536 + h * 64;
  for (int idx = tid; idx < 1536; idx += 256){
    int a = idx >> 9, rem = idx & 511;
    int tt = rem >> 3, c8 = (rem & 7) * 8;
    u32x4 w = *(const u32x4*)(base + (size_t)tt * 1536 + a * 512 + c8);
    float* dst = (a == 0) ? &Qs[tt][c8] : (a == 1) ? &Ks[tt][c8] : &Vs[tt][c8];
    #pragma unroll
    for (int j2 = 0; j2 < 4; ++j2){
      dst[2*j2]   = __uint_as_float(w[j2] << 16);
      dst[2*j2+1] = __uint_as_float(w[j2] & 0xffff0000u);
    }
  }
  __syncthreads();
  const int r = tid >> 2, cg = tid & 3;
  float qr[64];
  #pragma unroll
  for (int k4 = 0; k4 < 16; ++k4) *(f32x4*)&qr[k4*4] = *(const f32x4*)&Qs[r][k4*4];
  float sv[16];
  #pragma unroll
  for (int i = 0; i < 16; ++i){
    int c = cg * 16 + i;
    float acc = 0.f;
    #pragma unroll
    for (int k4 = 0; k4 < 16; ++k4){
      f32x4 kv = *(const f32x4*)&Ks[c][k4*4];
      acc += qr[k4*4+0]*kv.x + qr[k4*4+1]*kv.y + qr[k4*4+2]*kv.z + qr[k4*4+3]*kv.w;
    }
    sv[i] = acc * 0.125f;
  }
  float mx = -1e30f;
  #pragma unroll
  for (int i = 0; i < 16; ++i) mx = fmaxf(mx, sv[i]);
  mx = fmaxf(mx, __shfl_xor(mx, 1));
  mx = fmaxf(mx, __shfl_xor(mx, 2));
  float sum = 0.f;
  #pragma unroll
  for (int i = 0; i < 16; ++i){ sv[i] = __expf(sv[i] - mx); sum += sv[i]; }
  sum += __shfl_xor(sum, 1);
  sum += __shfl_xor(sum, 2);
  float inv = 1.f / sum;
  #pragma unroll
  for (int i = 0; i < 16; ++i) Ss[r][cg*16 + i] = sv[i] * inv;
  __syncthreads();
  float ar[64];
  #pragma unroll
  for (int k4 = 0; k4 < 16; ++k4) *(f32x4*)&ar[k4*4] = *(const f32x4*)&Ss[r][k4*4];
  f32x4 zz = {0.f,0.f,0.f,0.f};
  f32x4 o4[4]; o4[0]=zz; o4[1]=zz; o4[2]=zz; o4[3]=zz;
  for (int k = 0; k < 64; ++k){
    float s = ar[k];
    #pragma unroll
    for (int q = 0; q < 4; ++q){
      f32x4 v = *(const f32x4*)&Vs[k][cg*16 + q*4];
      o4[q] += v * s;
    }
  }
  ushort_t* op = Ob + ((size_t)(b * 64 + r)) * 512 + h * 64 + cg * 16;
  #pragma unroll
  for (int q = 0; q < 4; ++q){
    op[q*4+0] = f2bfbits(o4[q].x);
    op[q*4+1] = f2bfbits(o4[q].y);
    op[q*4+2] = f2bfbits(o4[q].z);
    op[q*4+3] = f2bfbits(o4[q].w);
  }
}

// ---------------------------------------------------------------------------
// LayerNorm over D=512, one wave per row; writes f32 X and bf16 Xb.
// ---------------------------------------------------------------------------
__global__ void __launch_bounds__(256) ln512_kernel(const float* __restrict__ R,
    const float* __restrict__ g, const float* __restrict__ bb,
    float* __restrict__ X, ushort_t* __restrict__ Xb)
{
  const int row  = blockIdx.x * 4 + (threadIdx.x >> 6);
  const int lane = threadIdx.x & 63;
  const float* p = R + (size_t)row * 512 + lane * 8;
  f32x4 u = *(const f32x4*)p;
  f32x4 v = *(const f32x4*)(p + 4);
  float s  = u.x+u.y+u.z+u.w + v.x+v.y+v.z+v.w;
  float sq = u.x*u.x+u.y*u.y+u.z*u.z+u.w*u.w + v.x*v.x+v.y*v.y+v.z*v.z+v.w*v.w;
  #pragma unroll
  for (int off = 1; off < 64; off <<= 1){
    s  += __shfl_xor(s, off);
    sq += __shfl_xor(sq, off);
  }
  float mu   = s  * (1.f/512.f);
  float var  = sq * (1.f/512.f) - mu*mu;
  float rstd = rsqrtf(var + LN_EPS);
  const float* gp = g  + lane * 8;
  const float* bp = bb + lane * 8;
  f32x4 g0 = *(const f32x4*)gp, g1v = *(const f32x4*)(gp+4);
  f32x4 b0 = *(const f32x4*)bp, b1v = *(const f32x4*)(bp+4);
  f32x4 o0, o1;
  o0.x=(u.x-mu)*rstd*g0.x+b0.x;  o0.y=(u.y-mu)*rstd*g0.y+b0.y;
  o0.z=(u.z-mu)*rstd*g0.z+b0.z;  o0.w=(u.w-mu)*rstd*g0.w+b0.w;
  o1.x=(v.x-mu)*rstd*g1v.x+b1v.x; o1.y=(v.y-mu)*rstd*g1v.y+b1v.y;
  o1.z=(v.z-mu)*rstd*g1v.z+b1v.z; o1.w=(v.w-mu)*rstd*g1v.w+b1v.w;
  float* xp = X + (size_t)row * 512 + lane * 8;
  *(f32x4*)xp       = o0;
  *(f32x4*)(xp + 4) = o1;
  u32x4 w;
  w[0]=pack2(o0.x,o0.y); w[1]=pack2(o0.z,o0.w); w[2]=pack2(o1.x,o1.y); w[3]=pack2(o1.z,o1.w);
  *(u32x4*)(Xb + (size_t)row * 512 + lane * 8) = w;
}

// ---------------------------------------------------------------------------
// Decoder helpers (single wave, 64 lanes)
// ---------------------------------------------------------------------------
// Build B-frags for matvec y = W@x: x occupies column 0 of B.
__device__ __forceinline__ void make_vec_bfrag(const float* __restrict__ x,
                                               int lane, bf16x8 bf[4]){
  const int kg = lane >> 4;
  const bool act = (lane & 15) == 0;
  bf16x8 z8 = {0,0,0,0,0,0,0,0};
  #pragma unroll
  for (int kb = 0; kb < 4; ++kb){
    f32x4 u = *(const f32x4*)(x + kb*32 + kg*8);
    f32x4 v = *(const f32x4*)(x + kb*32 + kg*8 + 4);
    bf16x8 r = pack8(u, v);
    bf[kb] = act ? r : z8;
  }
}

// y[0..127] = W[128x128] @ x + bias (W bf16 global row-major, bias/dst LDS f32)
__device__ __forceinline__ void matvec128(const ushort_t* __restrict__ Wg,
    const float* __restrict__ x, const float* __restrict__ biasLds,
    float* __restrict__ dst, int lane){
  const int col = lane & 15, kg = lane >> 4;
  bf16x8 xb[4];
  make_vec_bfrag(x, lane, xb);
  #pragma unroll
  for (int rt = 0; rt < 8; ++rt){
    f32x4 acc = {0.f,0.f,0.f,0.f};
    const ushort_t* wp = Wg + (rt*16 + col)*128 + kg*8;
    #pragma unroll
    for (int kb = 0; kb < 4; ++kb)
      acc = __builtin_amdgcn_mfma_f32_16x16x32_bf16(*(const bf16x8*)(wp + kb*32), xb[kb], acc, 0,0,0);
    if (col == 0){
      int r0 = rt*16 + kg*4;
      f32x4 o = acc + *(const f32x4*)(biasLds + r0);
      *(f32x4*)(dst + r0) = o;
    }
  }
}

// scores[h][j] = 0.25 * q[h*16..] . K[j][h*16..]   (8 heads, 64 j, dh=16)
// 2 heads per MFMA: B col0 = lo-head (k<16), col1 = hi-head (k>=16).
__device__ __forceinline__ void scores_mfma(const ushort_t* __restrict__ K,
    const float* __restrict__ q, float* __restrict__ sc, int lane){
  const int col = lane & 15, kg = lane >> 4;
  const bool bval = (col == 0 && kg < 2) || (col == 1 && kg >= 2);
  bf16x8 z8 = {0,0,0,0,0,0,0,0};
  f32x4 z4 = {0.f,0.f,0.f,0.f};
  #pragma unroll
  for (int hp = 0; hp < 4; ++hp){
    f32x4 u = *(const f32x4*)(q + hp*32 + kg*8);
    f32x4 v = *(const f32x4*)(q + hp*32 + kg*8 + 4);
    u *= 0.25f; v *= 0.25f;
    bf16x8 qb = pack8(u, v);
    qb = bval ? qb : z8;
    #pragma unroll
    for (int jt = 0; jt < 4; ++jt){
      bf16x8 a = *(const bf16x8*)(K + (jt*16 + col)*KC_STRIDE + hp*32 + kg*8);
      f32x4 d = __builtin_amdgcn_mfma_f32_16x16x32_bf16(a, qb, z4, 0,0,0);
      if (col < 2)
        *(f32x4*)(sc + (hp*2 + col)*SC_STRIDE + jt*16 + kg*4) = d;
    }
  }
}

// o[d] = sum_j p[head(d)][j] * V[j][d], via transposed V cache (VT[d][j]).
__device__ __forceinline__ void wv_mfma(const ushort_t* __restrict__ VT,
    const float* __restrict__ p, float* __restrict__ o, int lane){
  const int col = lane & 15, kg = lane >> 4;
  bf16x8 z8 = {0,0,0,0,0,0,0,0};
  #pragma unroll
  for (int h = 0; h < 8; ++h){
    f32x4 acc = {0.f,0.f,0.f,0.f};
    #pragma unroll
    for (int jb = 0; jb < 2; ++jb){
      f32x4 u = *(const f32x4*)(p + h*SC_STRIDE + jb*32 + kg*8);
      f32x4 v = *(const f32x4*)(p + h*SC_STRIDE + jb*32 + kg*8 + 4);
      bf16x8 pb = pack8(u, v);
      pb = (col == 0) ? pb : z8;
      bf16x8 a = *(const bf16x8*)(VT + (h*16 + col)*VT_STRIDE + jb*32 + kg*8);
      acc = __builtin_amdgcn_mfma_f32_16x16x32_bf16(a, pb, acc, 0,0,0);
    }
    if (col == 0)
      *(f32x4*)(o + h*16 + kg*4) = acc;
  }
}

// LayerNorm over 128 LDS values, in-wave (lane owns elems lane, lane+64)
__device__ __forceinline__ void ln_wave(const float* __restrict__ in,
    const float* __restrict__ resid, const float* __restrict__ g,
    const float* __restrict__ bb, float* __restrict__ out, int lane){
  float a0 = in[lane]      + resid[lane];
  float a1 = in[lane + 64] + resid[lane + 64];
  float s = a0 + a1, sq = a0*a0 + a1*a1;
  #pragma unroll
  for (int off = 1; off < 64; off <<= 1){
    s  += __shfl_xor(s, off);
    sq += __shfl_xor(sq, off);
  }
  float mu = s * (1.f/128.f);
  float var = sq * (1.f/128.f) - mu*mu;
  float rs = rsqrtf(var + LN_EPS);
  out[lane]      = (a0 - mu)*rs*g[lane]      + bb[lane];
  out[lane + 64] = (a1 - mu)*rs*g[lane + 64] + bb[lane + 64];
}

// ---------------------------------------------------------------------------
// Decoder: ONE WAVE per batch. 64 serial steps, all contractions via MFMA.
// ---------------------------------------------------------------------------
__global__ void __launch_bounds__(64) decode_kernel(
    const ushort_t* __restrict__ MEMb,        // [32*64][128] bf16
    const ushort_t* __restrict__ Wsaqkv,      // [384][128] bf16
    const ushort_t* __restrict__ Wsaout,      // [128][128]
    const ushort_t* __restrict__ Wcaqkv,      // [384][128]: rows 0-127 q, 128-383 kv
    const ushort_t* __restrict__ Wcaout,      // [128][128]
    const ushort_t* __restrict__ Wff1,        // [16][128]
    const ushort_t* __restrict__ Wff2,        // [128][16] (+pad)
    const float* __restrict__ saqkv_b, const float* __restrict__ saout_b,
    const float* __restrict__ caqkv_b, const float* __restrict__ caout_b,
    const float* __restrict__ f1b, const float* __restrict__ f2b,
    const float* __restrict__ g1, const float* __restrict__ b1,
    const float* __restrict__ g2, const float* __restrict__ b2,
    const float* __restrict__ g3, const float* __restrict__ b3,
    float* __restrict__ Out)
{
  __shared__ __attribute__((aligned(16))) ushort_t Ksa[64*KC_STRIDE];
  __shared__ __attribute__((aligned(16))) ushort_t VsaT[128*VT_STRIDE];
  __shared__ __attribute__((aligned(16))) ushort_t Kc [64*KC_STRIDE];
  __shared__ __attribute__((aligned(16))) ushort_t VcT[128*VT_STRIDE];
  __shared__ __attribute__((aligned(16))) float scores[8*SC_STRIDE];
  __shared__ __attribute__((aligned(16))) float pbuf[8*SC_STRIDE];
  __shared__ __attribute__((aligned(16))) float xcur[128], x1[128], x2[128];
  __shared__ __attribute__((aligned(16))) float qbuf[128], obuf[128], rtmp[128];
  __shared__ __attribute__((aligned(16))) float hbuf[32];
  __shared__ __attribute__((aligned(16))) float bsaq[384];
  __shared__ __attribute__((aligned(16))) float bsao[128], bcaq[128], bcakv[256], bcao[128];
  __shared__ __attribute__((aligned(16))) float bff1[16], bff2[128];
  __shared__ __attribute__((aligned(16))) float lg1[128], lb1[128], lg2[128], lb2[128], lg3[128], lb3[128];

  const int lane = threadIdx.x;
  const int col = lane & 15, kg = lane >> 4;
  const int b = blockIdx.x;
  f32x4 z4 = {0.f,0.f,0.f,0.f};

  // --- preamble: params + zero-init ---
  for (int i = lane; i < 384; i += 64) bsaq[i] = saqkv_b[i];
  for (int i = lane; i < 256; i += 64) bcakv[i] = caqkv_b[128 + i];
  for (int i = lane; i < 128; i += 64){
    bsao[i] = saout_b[i]; bcaq[i] = caqkv_b[i]; bcao[i] = caout_b[i]; bff2[i] = f2b[i];
    lg1[i]=g1[i]; lb1[i]=b1[i]; lg2[i]=g2[i]; lb2[i]=b2[i]; lg3[i]=g3[i]; lb3[i]=b3[i];
    xcur[i] = 0.f;   // tgt row 0 is zero
  }
  if (lane < 16) bff1[lane] = f1b[lane];
  if (lane < 32) hbuf[lane] = 0.f;   // pad [16..31] stays 0 forever
  // zero VsaT: never-written columns j>t must be finite (p=0 * NaN hazard)
  for (int i = lane; i < 128*VT_STRIDE; i += 64) VsaT[i] = 0;
  __syncthreads();

  // --- preamble: cross-attn K/V = Wkv @ mem^T via MFMA (real GEMM 256x128x64)
  {
    const ushort_t* Wkv = Wcaqkv + 128*128;
    const ushort_t* memb = MEMb + (size_t)b * 64 * 128;
    #pragma unroll 2
    for (int rt = 0; rt < 16; ++rt){
      #pragma unroll
      for (int jt = 0; jt < 4; ++jt){
        f32x4 acc = z4;
        #pragma unroll
        for (int kb = 0; kb < 4; ++kb){
          bf16x8 a  = *(const bf16x8*)(Wkv  + (rt*16 + col)*128 + kb*32 + kg*8);
          bf16x8 bb = *(const bf16x8*)(memb + (size_t)(jt*16 + col)*128 + kb*32 + kg*8);
          acc = __builtin_amdgcn_mfma_f32_16x16x32_bf16(a, bb, acc, 0,0,0);
        }
        int j  = jt*16 + col;           // D col = mem row
        int r0 = rt*16 + kg*4;          // D rows = W rows
        f32x4 o = acc + *(const f32x4*)(bcakv + r0);
        if (r0 < 128){
          ushort_t* p = Kc + j*KC_STRIDE + r0;
          p[0]=f2bfbits(o.x); p[1]=f2bfbits(o.y); p[2]=f2bfbits(o.z); p[3]=f2bfbits(o.w);
        } else {
          int d = r0 - 128;
          VcT[(d+0)*VT_STRIDE + j] = f2bfbits(o.x);
          VcT[(d+1)*VT_STRIDE + j] = f2bfbits(o.y);
          VcT[(d+2)*VT_STRIDE + j] = f2bfbits(o.z);
          VcT[(d+3)*VT_STRIDE + j] = f2bfbits(o.w);
        }
      }
    }
  }

  for (int t = 0; t < 64; ++t){
    __syncthreads();
    // A: SA qkv (384x128 matvec). q -> qbuf; K -> Ksa[t]; V -> VsaT[.][t].
    // At t=0 this writes slot 0 = zero-row K/V (= bias) exactly.
    {
      bf16x8 xb[4];
      make_vec_bfrag(xcur, lane, xb);
      #pragma unroll 4
      for (int rt = 0; rt < 24; ++rt){
        f32x4 acc = z4;
        const ushort_t* wp = Wsaqkv + (rt*16 + col)*128 + kg*8;
        #pragma unroll
        for (int kb = 0; kb < 4; ++kb)
          acc = __builtin_amdgcn_mfma_f32_16x16x32_bf16(*(const bf16x8*)(wp + kb*32), xb[kb], acc, 0,0,0);
        if (col == 0){
          int r0 = rt*16 + kg*4;
          f32x4 o = acc + *(const f32x4*)(bsaq + r0);
          if (r0 < 128){
            *(f32x4*)(qbuf + r0) = o;
          } else if (r0 < 256){
            ushort_t* p = Ksa + t*KC_STRIDE + (r0 - 128);
            p[0]=f2bfbits(o.x); p[1]=f2bfbits(o.y); p[2]=f2bfbits(o.z); p[3]=f2bfbits(o.w);
          } else {
            int d = r0 - 256;
            VsaT[(d+0)*VT_STRIDE + t] = f2bfbits(o.x);
            VsaT[(d+1)*VT_STRIDE + t] = f2bfbits(o.y);
            VsaT[(d+2)*VT_STRIDE + t] = f2bfbits(o.z);
            VsaT[(d+3)*VT_STRIDE + t] = f2bfbits(o.w);
          }
        }
      }
    }
    __syncthreads();
    scores_mfma(Ksa, qbuf, scores, lane);
    __syncthreads();
    // SA softmax: j=0 is the zero-row with multiplicity (65-t); valid j<=t.
    {
      const int h = lane >> 3, jj = lane & 7;
      float sv[8];
      *(f32x4*)(sv)     = *(const f32x4*)(scores + h*SC_STRIDE + jj*8);
      *(f32x4*)(sv + 4) = *(const f32x4*)(scores + h*SC_STRIDE + jj*8 + 4);
      #pragma unroll
      for (int i = 0; i < 8; ++i){ int j = jj*8 + i; sv[i] = (j <= t) ? sv[i] : -1e30f; }
      float mx = sv[0];
      #pragma unroll
      for (int i = 1; i < 8; ++i) mx = fmaxf(mx, sv[i]);
      mx = fmaxf(mx, __shfl_xor(mx, 1));
      mx = fmaxf(mx, __shfl_xor(mx, 2));
      mx = fmaxf(mx, __shfl_xor(mx, 4));
      float e[8];
      #pragma unroll
      for (int i = 0; i < 8; ++i) e[i] = __expf(sv[i] - mx);
      if (jj == 0) e[0] *= (float)(65 - t);
      float sum = 0.f;
      #pragma unroll
      for (int i = 0; i < 8; ++i) sum += e[i];
      sum += __shfl_xor(sum, 1);
      sum += __shfl_xor(sum, 2);
      sum += __shfl_xor(sum, 4);
      float inv = 1.f / sum;
      f32x4 p0 = {e[0]*inv, e[1]*inv, e[2]*inv, e[3]*inv};
      f32x4 p1 = {e[4]*inv, e[5]*inv, e[6]*inv, e[7]*inv};
      *(f32x4*)(pbuf + h*SC_STRIDE + jj*8)     = p0;
      *(f32x4*)(pbuf + h*SC_STRIDE + jj*8 + 4) = p1;
    }
    __syncthreads();
    wv_mfma(VsaT, pbuf, obuf, lane);
    __syncthreads();
    matvec128(Wsaout, obuf, bsao, rtmp, lane);
    __syncthreads();
    ln_wave(rtmp, xcur, lg1, lb1, x1, lane);
    __syncthreads();
    matvec128(Wcaqkv, x1, bcaq, qbuf, lane);   // rows 0..127 = q
    __syncthreads();
    scores_mfma(Kc, qbuf, scores, lane);
    __syncthreads();
    // CA softmax: all 64 valid
    {
      const int h = lane >> 3, jj = lane & 7;
      float sv[8];
      *(f32x4*)(sv)     = *(const f32x4*)(scores + h*SC_STRIDE + jj*8);
      *(f32x4*)(sv + 4) = *(const f32x4*)(scores + h*SC_STRIDE + jj*8 + 4);
      float mx = sv[0];
      #pragma unroll
      for (int i = 1; i < 8; ++i) mx = fmaxf(mx, sv[i]);
      mx = fmaxf(mx, __shfl_xor(mx, 1));
      mx = fmaxf(mx, __shfl_xor(mx, 2));
      mx = fmaxf(mx, __shfl_xor(mx, 4));
      float e[8], sum = 0.f;
      #pragma unroll
      for (int i = 0; i < 8; ++i){ e[i] = __expf(sv[i] - mx); sum += e[i]; }
      sum += __shfl_xor(sum, 1);
      sum += __shfl_xor(sum, 2);
      sum += __shfl_xor(sum, 4);
      float inv = 1.f / sum;
      f32x4 p0 = {e[0]*inv, e[1]*inv, e[2]*inv, e[3]*inv};
      f32x4 p1 = {e[4]*inv, e[5]*inv, e[6]*inv, e[7]*inv};
      *(f32x4*)(pbuf + h*SC_STRIDE + jj*8)     = p0;
      *(f32x4*)(pbuf + h*SC_STRIDE + jj*8 + 4) = p1;
    }
    __syncthreads();
    wv_mfma(VcT, pbuf, obuf, lane);
    __syncthreads();
    matvec128(Wcaout, obuf, bcao, rtmp, lane);
    __syncthreads();
    ln_wave(rtmp, x1, lg2, lb2, x2, lane);
    __syncthreads();
    // FF1: 16x128 matvec + relu
    {
      bf16x8 xb[4];
      make_vec_bfrag(x2, lane, xb);
      f32x4 acc = z4;
      const ushort_t* wp = Wff1 + col*128 + kg*8;
      #pragma unroll
      for (int kb = 0; kb < 4; ++kb)
        acc = __builtin_amdgcn_mfma_f32_16x16x32_bf16(*(const bf16x8*)(wp + kb*32), xb[kb], acc, 0,0,0);
      if (col == 0){
        int r0 = kg*4;
        f32x4 o = acc + *(const f32x4*)(bff1 + r0);
        hbuf[r0+0]=fmaxf(o.x,0.f); hbuf[r0+1]=fmaxf(o.y,0.f);
        hbuf[r0+2]=fmaxf(o.z,0.f); hbuf[r0+3]=fmaxf(o.w,0.f);
      }
    }
    __syncthreads();
    // FF2: 128 rows, K=16 (padded to 32 with zeros in hbuf[16..31])
    {
      f32x4 u = *(const f32x4*)(hbuf + kg*8);
      f32x4 v = *(const f32x4*)(hbuf + kg*8 + 4);
      bf16x8 hb = pack8(u, v);
      bf16x8 z8 = {0,0,0,0,0,0,0,0};
      hb = (col == 0) ? hb : z8;
      #pragma unroll
      for (int rt = 0; rt < 8; ++rt){
        const ushort_t* wp = Wff2 + (rt*16 + col)*16 + kg*8;  // kg>=2 reads pad x B=0
        f32x4 acc = __builtin_amdgcn_mfma_f32_16x16x32_bf16(*(const bf16x8*)wp, hb, z4, 0,0,0);
        if (col == 0){
          int r0 = rt*16 + kg*4;
          *(f32x4*)(rtmp + r0) = acc + *(const f32x4*)(bff2 + r0);
        }
      }
    }
    __syncthreads();
    ln_wave(rtmp, x2, lg3, lb3, xcur, lane);
    // Out row t = new xcur (this lane wrote xcur[lane], xcur[lane+64])
    Out[((size_t)(b*64 + t))*128 + lane]      = xcur[lane];
    Out[((size_t)(b*64 + t))*128 + lane + 64] = xcur[lane + 64];
  }
}

// ---------------------------------------------------------------------------
extern "C" void kernel_launch(void* const* d_in, const int* in_sizes, int n_in,
                              void* d_out, int out_size, void* d_ws, size_t ws_size,
                              hipStream_t stream)
{
  (void)in_sizes; (void)n_in; (void)out_size; (void)ws_size;
  const float* src   = (const float*)d_in[0];
  const float* eqkvw = (const float*)d_in[1];
  const float* eqkvb = (const float*)d_in[2];
  const float* eow   = (const float*)d_in[3];
  const float* eob   = (const float*)d_in[4];
  const float* ef1w  = (const float*)d_in[5];
  const float* ef1b  = (const float*)d_in[6];
  const float* ef2w  = (const float*)d_in[7];
  const float* ef2b  = (const float*)d_in[8];
  const float* eg1   = (const float*)d_in[9];
  const float* eb1   = (const float*)d_in[10];
  const float* eg2   = (const float*)d_in[11];
  const float* eb2   = (const float*)d_in[12];
  const float* fcw   = (const float*)d_in[13];
  const float* fcb   = (const float*)d_in[14];
  const float* dsaqw = (const float*)d_in[15];
  const float* dsaqb = (const float*)d_in[16];
  const float* dsaow = (const float*)d_in[17];
  const float* dsaob = (const float*)d_in[18];
  const float* dcaqw = (const float*)d_in[19];
  const float* dcaqb = (const float*)d_in[20];
  const float* dcaow = (const float*)d_in[21];
  const float* dcaob = (const float*)d_in[22];
  const float* df1w  = (const float*)d_in[23];
  const float* df1b  = (const float*)d_in[24];
  const float* df2w  = (const float*)d_in[25];
  const float* df2b  = (const float*)d_in[26];
  const float* dg1   = (const float*)d_in[27];
  const float* db1   = (const float*)d_in[28];
  const float* dg2   = (const float*)d_in[29];
  const float* db2   = (const float*)d_in[30];
  const float* dg3   = (const float*)d_in[31];
  const float* db3   = (const float*)d_in[32];

  // ws layout (float offsets). Total 6,195,216 fl = 24.78 MB (within the
  // 25.2 MB envelope proven in round 0).
  float* ws = (float*)d_ws;
  ushort_t* QKVb   = (ushort_t*)ws;              // [2048][1536] bf16 (enc, per layer)
  float*    Rb     = ws;                         // [2048][512] f32, overlays dead QKVb
  float*    XA     = ws + 1572864;               // [2048][512] f32
  float*    XB     = ws + 2621440;               // [2048][512] f32
  ushort_t* Xinb   = (ushort_t*)(ws + 3670016);  // [2048][512] bf16 (layer input / fc input)
  ushort_t* Ob     = (ushort_t*)(ws + 4194304);  // [2048][512] bf16 (attn out)
  ushort_t* XBb    = (ushort_t*)(ws + 4718592);  // [2048][512] bf16
  ushort_t* Hb     = (ushort_t*)(ws + 5242880);  // [2048][64] bf16
  ushort_t* MEMbb  = (ushort_t*)(ws + 5308416);  // [2048][128] bf16
  ushort_t* eqkvw_l= (ushort_t*)(ws + 5439488);  // [1536][512] bf16, per-layer
  ushort_t* eow_l  = (ushort_t*)(ws + 5832704);  // [512][512] bf16, per-layer
  ushort_t* ef1w_b = (ushort_t*)(ws + 5963776);  // [4][64][512] bf16 (all layers)
  ushort_t* ef2w_b = (ushort_t*)(ws + 6029312);  // [4][512][64] bf16
  ushort_t* fcw_b  = (ushort_t*)(ws + 6094848);  // [128][512] bf16
  ushort_t* dsaqw_b  = (ushort_t*)(ws + 6127616);
  ushort_t* dsaow_b  = (ushort_t*)(ws + 6152192);
  ushort_t* dcaqkv_b = (ushort_t*)(ws + 6160384);
  ushort_t* dcaow_b  = (ushort_t*)(ws + 6184960);
  ushort_t* df1w_b   = (ushort_t*)(ws + 6193152);
  ushort_t* df2w_b   = (ushort_t*)(ws + 6194176); // 2048 + 32 pad

  // prolog: batched f32->bf16 conversions (src + all layer-invariant weights)
  cvt10<<<dim3(512,10),256,0,stream>>>(
      src,   Xinb,    1048576,
      ef1w,  ef1w_b,  131072,
      ef2w,  ef2w_b,  131072,
      fcw,   fcw_b,   65536,
      dsaqw, dsaqw_b, 49152,
      dsaow, dsaow_b, 16384,
      dcaqw, dcaqkv_b,49152,
      dcaow, dcaow_b, 16384,
      df1w,  df1w_b,  2048,
      df2w,  df2w_b,  2048);

  const float* Xres = src;
  for (int l = 0; l < 4; ++l){
    cvt10<<<dim3(384,2),256,0,stream>>>(
        eqkvw + (size_t)l*786432, eqkvw_l, 786432,
        eow   + (size_t)l*262144, eow_l,   262144,
        nullptr,nullptr,0, nullptr,nullptr,0, nullptr,nullptr,0,
        nullptr,nullptr,0, nullptr,nullptr,0, nullptr,nullptr,0,
        nullptr,nullptr,0, nullptr,nullptr,0);
    gemm_bf16<<<dim3(32,24),256,0,stream>>>(Xinb, eqkvw_l, eqkvb + l*1536, nullptr,
                                            nullptr, QKVb, 2048, 1536, 512, 0);
    enc_attn_kernel<<<dim3(32,8),256,0,stream>>>(QKVb, Ob);
    gemm_bf16<<<dim3(32,8),256,0,stream>>>(Ob, eow_l, eob + l*512, Xres,
                                           Rb, nullptr, 2048, 512, 512, 0);
    ln512_kernel<<<dim3(512),256,0,stream>>>(Rb, eg1 + l*512, eb1 + l*512, XB, XBb);
    gemm_bf16<<<dim3(32,1),256,0,stream>>>(XBb, ef1w_b + (size_t)l*32768, ef1b + l*64,
                                           nullptr, nullptr, Hb, 2048, 64, 512, 1);
    gemm_bf16<<<dim3(32,8),256,0,stream>>>(Hb, ef2w_b + (size_t)l*32768, ef2b + l*512,
                                           XB, Rb, nullptr, 2048, 512, 64, 0);
    ln512_kernel<<<dim3(512),256,0,stream>>>(Rb, eg2 + l*512, eb2 + l*512, XA, Xinb);
    Xres = XA;
  }
  gemm_bf16<<<dim3(32,2),256,0,stream>>>(Xinb, fcw_b, fcb, nullptr,
                                         nullptr, MEMbb, 2048, 128, 512, 0);
  decode_kernel<<<dim3(32),64,0,stream>>>(MEMbb,
      dsaqw_b, dsaow_b, dcaqkv_b, dcaow_b, df1w_b, df2w_b,
      dsaqb, dsaob, dcaqb, dcaob, df1b, df2b,
      dg1, db1, dg2, db2, dg3, db3, (float*)d_out);
}

// Round 11
// 841.834 us; speedup vs baseline: 2.5166x; 2.2298x over previous
//
#include <hip/hip_runtime.h>
#include <hip/hip_bf16.h>

// CustomTransformer: 4-layer encoder (d=512, ff=64) + fc(512->128) + 64-step
// decoder scan. Decoder v3: 8 waves per batch; ALL decoder weights live in
// REGISTERS (loaded once, reused 64 steps); per-phase work split across waves
// (matvec row-tiles, score jt-tiles, PV heads); K/V caches in LDS bf16.
// Zero-row reduction: at step t the 65-t zero rows of tgt share K/V = bias ->
// slot j=0 holds the zero-row with multiplicity (65-t).

typedef __attribute__((ext_vector_type(8))) short bf16x8;
typedef __attribute__((ext_vector_type(4))) float f32x4;
typedef __attribute__((ext_vector_type(4))) unsigned int u32x4;
typedef unsigned short ushort_t;
typedef unsigned int uint_t;

#define LN_EPS 1e-5f
#define KC_STRIDE 136   // bf16 elems; 272B = 68 words == 4 mod 32 -> uniform banks
#define VT_STRIDE 72    // bf16 elems; 144B = 36 words == 4 mod 32 -> uniform banks
#define SC_STRIDE 72    // f32 elems

__device__ __forceinline__ ushort_t f2bfbits(float f){
  union { __hip_bfloat16 h; ushort_t u; } cv;
  cv.h = __float2bfloat16(f);   // RNE
  return cv.u;
}
__device__ __forceinline__ uint_t pack2(float a, float b){
  return (uint_t)f2bfbits(a) | ((uint_t)f2bfbits(b) << 16);
}
__device__ __forceinline__ bf16x8 pack8(f32x4 u, f32x4 v){
  bf16x8 r;
  r[0]=(short)f2bfbits(u.x); r[1]=(short)f2bfbits(u.y);
  r[2]=(short)f2bfbits(u.z); r[3]=(short)f2bfbits(u.w);
  r[4]=(short)f2bfbits(v.x); r[5]=(short)f2bfbits(v.y);
  r[6]=(short)f2bfbits(v.z); r[7]=(short)f2bfbits(v.w);
  return r;
}

// ---------------------------------------------------------------------------
// Batched f32 -> bf16 conversion (up to 10 tensors, selected by blockIdx.y)
// ---------------------------------------------------------------------------
__global__ void __launch_bounds__(256) cvt10(
    const float* s0, ushort_t* d0, int n0,
    const float* s1, ushort_t* d1, int n1,
    const float* s2, ushort_t* d2, int n2,
    const float* s3, ushort_t* d3, int n3,
    const float* s4, ushort_t* d4, int n4,
    const float* s5, ushort_t* d5, int n5,
    const float* s6, ushort_t* d6, int n6,
    const float* s7, ushort_t* d7, int n7,
    const float* s8, ushort_t* d8, int n8,
    const float* s9, ushort_t* d9, int n9)
{
  const float* s; ushort_t* d; int n;
  switch (blockIdx.y){
    case 0: s=s0; d=d0; n=n0; break;
    case 1: s=s1; d=d1; n=n1; break;
    case 2: s=s2; d=d2; n=n2; break;
    case 3: s=s3; d=d3; n=n3; break;
    case 4: s=s4; d=d4; n=n4; break;
    case 5: s=s5; d=d5; n=n5; break;
    case 6: s=s6; d=d6; n=n6; break;
    case 7: s=s7; d=d7; n=n7; break;
    case 8: s=s8; d=d8; n=n8; break;
    default: s=s9; d=d9; n=n9; break;
  }
  for (int i = (blockIdx.x*256 + threadIdx.x)*8; i < n; i += gridDim.x*256*8){
    f32x4 u = *(const f32x4*)(s + i);
    f32x4 v = *(const f32x4*)(s + i + 4);
    u32x4 w;
    w[0]=pack2(u.x,u.y); w[1]=pack2(u.z,u.w); w[2]=pack2(v.x,v.y); w[3]=pack2(v.z,v.w);
    *(u32x4*)(d + i) = w;
  }
}

// ---------------------------------------------------------------------------
// Encoder GEMM: C[M,N] = A[M,K] @ W[N,K]^T (+bias)(+resid f32)(relu)
// ---------------------------------------------------------------------------
__global__ void __launch_bounds__(256) gemm_bf16(
    const ushort_t* __restrict__ A, const ushort_t* __restrict__ W,
    const float* __restrict__ bias, const float* __restrict__ resid,
    float* __restrict__ C, ushort_t* __restrict__ Cb,
    int M, int N, int K, int relu)
{
  const int tid  = threadIdx.x;
  const int lane = tid & 63;
  const int wid  = tid >> 6;
  const int rowBase = blockIdx.x * 64 + (wid >> 1) * 32;
  const int colBase = blockIdx.y * 64 + (wid & 1) * 32;
  const int r16 = lane & 15;
  const int kg  = lane >> 4;

  f32x4 zz = {0.f,0.f,0.f,0.f};
  f32x4 acc[2][2];
  acc[0][0]=zz; acc[0][1]=zz; acc[1][0]=zz; acc[1][1]=zz;

  const ushort_t* Ap = A + (size_t)(rowBase + r16) * K + kg*8;
  const ushort_t* Wp = W + (size_t)(colBase + r16) * K + kg*8;
  #pragma unroll 4
  for (int k0 = 0; k0 < K; k0 += 32){
    bf16x8 af0 = *(const bf16x8*)(Ap + k0);
    bf16x8 af1 = *(const bf16x8*)(Ap + (size_t)16*K + k0);
    bf16x8 bf0 = *(const bf16x8*)(Wp + k0);
    bf16x8 bf1 = *(const bf16x8*)(Wp + (size_t)16*K + k0);
    acc[0][0] = __builtin_amdgcn_mfma_f32_16x16x32_bf16(af0, bf0, acc[0][0], 0,0,0);
    acc[0][1] = __builtin_amdgcn_mfma_f32_16x16x32_bf16(af0, bf1, acc[0][1], 0,0,0);
    acc[1][0] = __builtin_amdgcn_mfma_f32_16x16x32_bf16(af1, bf0, acc[1][0], 0,0,0);
    acc[1][1] = __builtin_amdgcn_mfma_f32_16x16x32_bf16(af1, bf1, acc[1][1], 0,0,0);
  }

  #pragma unroll
  for (int mt = 0; mt < 2; ++mt)
  #pragma unroll
  for (int nt = 0; nt < 2; ++nt)
  #pragma unroll
  for (int i = 0; i < 4; ++i){
    int row = rowBase + mt*16 + kg*4 + i;   // C/D: row=(lane>>4)*4+i
    int col = colBase + nt*16 + r16;        //      col=lane&15
    float v = acc[mt][nt][i] + bias[col];
    if (resid) v += resid[(size_t)row * N + col];
    if (relu)  v = fmaxf(v, 0.f);
    if (C)  C[(size_t)row * N + col] = v;
    if (Cb) Cb[(size_t)row * N + col] = f2bfbits(v);
  }
}

// ---------------------------------------------------------------------------
// Encoder attention: one block per (batch, head). dh=64, S=64, scale=1/8.
// ---------------------------------------------------------------------------
#define APAD 68
__global__ void __launch_bounds__(256) enc_attn_kernel(
    const ushort_t* __restrict__ QKVb, ushort_t* __restrict__ Ob)
{
  __shared__ __attribute__((aligned(16))) float Qs[64][APAD];
  __shared__ __attribute__((aligned(16))) float Ks[64][APAD];
  __shared__ __attribute__((aligned(16))) float Vs[64][APAD];
  __shared__ __attribute__((aligned(16))) float Ss[64][APAD];
  const int b = blockIdx.x, h = blockIdx.y;
  const int tid = threadIdx.x;
  const ushort_t* base = QKVb + (size_t)b * 64 * 1536 + h * 64;
  for (int idx = tid; idx < 1536; idx += 256){
    int a = idx >> 9, rem = idx & 511;
    int tt = rem >> 3, c8 = (rem & 7) * 8;
    u32x4 w = *(const u32x4*)(base + (size_t)tt * 1536 + a * 512 + c8);
    float* dst = (a == 0) ? &Qs[tt][c8] : (a == 1) ? &Ks[tt][c8] : &Vs[tt][c8];
    #pragma unroll
    for (int j2 = 0; j2 < 4; ++j2){
      dst[2*j2]   = __uint_as_float(w[j2] << 16);
      dst[2*j2+1] = __uint_as_float(w[j2] & 0xffff0000u);
    }
  }
  __syncthreads();
  const int r = tid >> 2, cg = tid & 3;
  float qr[64];
  #pragma unroll
  for (int k4 = 0; k4 < 16; ++k4) *(f32x4*)&qr[k4*4] = *(const f32x4*)&Qs[r][k4*4];
  float sv[16];
  #pragma unroll
  for (int i = 0; i < 16; ++i){
    int c = cg * 16 + i;
    float acc = 0.f;
    #pragma unroll
    for (int k4 = 0; k4 < 16; ++k4){
      f32x4 kv = *(const f32x4*)&Ks[c][k4*4];
      acc += qr[k4*4+0]*kv.x + qr[k4*4+1]*kv.y + qr[k4*4+2]*kv.z + qr[k4*4+3]*kv.w;
    }
    sv[i] = acc * 0.125f;
  }
  float mx = -1e30f;
  #pragma unroll
  for (int i = 0; i < 16; ++i) mx = fmaxf(mx, sv[i]);
  mx = fmaxf(mx, __shfl_xor(mx, 1));
  mx = fmaxf(mx, __shfl_xor(mx, 2));
  float sum = 0.f;
  #pragma unroll
  for (int i = 0; i < 16; ++i){ sv[i] = __expf(sv[i] - mx); sum += sv[i]; }
  sum += __shfl_xor(sum, 1);
  sum += __shfl_xor(sum, 2);
  float inv = 1.f / sum;
  #pragma unroll
  for (int i = 0; i < 16; ++i) Ss[r][cg*16 + i] = sv[i] * inv;
  __syncthreads();
  float ar[64];
  #pragma unroll
  for (int k4 = 0; k4 < 16; ++k4) *(f32x4*)&ar[k4*4] = *(const f32x4*)&Ss[r][k4*4];
  f32x4 zz = {0.f,0.f,0.f,0.f};
  f32x4 o4[4]; o4[0]=zz; o4[1]=zz; o4[2]=zz; o4[3]=zz;
  for (int k = 0; k < 64; ++k){
    float s = ar[k];
    #pragma unroll
    for (int q = 0; q < 4; ++q){
      f32x4 v = *(const f32x4*)&Vs[k][cg*16 + q*4];
      o4[q] += v * s;
    }
  }
  ushort_t* op = Ob + ((size_t)(b * 64 + r)) * 512 + h * 64 + cg * 16;
  #pragma unroll
  for (int q = 0; q < 4; ++q){
    op[q*4+0] = f2bfbits(o4[q].x);
    op[q*4+1] = f2bfbits(o4[q].y);
    op[q*4+2] = f2bfbits(o4[q].z);
    op[q*4+3] = f2bfbits(o4[q].w);
  }
}

// ---------------------------------------------------------------------------
// LayerNorm over D=512, one wave per row; writes f32 X and bf16 Xb.
// ---------------------------------------------------------------------------
__global__ void __launch_bounds__(256) ln512_kernel(const float* __restrict__ R,
    const float* __restrict__ g, const float* __restrict__ bb,
    float* __restrict__ X, ushort_t* __restrict__ Xb)
{
  const int row  = blockIdx.x * 4 + (threadIdx.x >> 6);
  const int lane = threadIdx.x & 63;
  const float* p = R + (size_t)row * 512 + lane * 8;
  f32x4 u = *(const f32x4*)p;
  f32x4 v = *(const f32x4*)(p + 4);
  float s  = u.x+u.y+u.z+u.w + v.x+v.y+v.z+v.w;
  float sq = u.x*u.x+u.y*u.y+u.z*u.z+u.w*u.w + v.x*v.x+v.y*v.y+v.z*v.z+v.w*v.w;
  #pragma unroll
  for (int off = 1; off < 64; off <<= 1){
    s  += __shfl_xor(s, off);
    sq += __shfl_xor(sq, off);
  }
  float mu   = s  * (1.f/512.f);
  float var  = sq * (1.f/512.f) - mu*mu;
  float rstd = rsqrtf(var + LN_EPS);
  const float* gp = g  + lane * 8;
  const float* bp = bb + lane * 8;
  f32x4 g0 = *(const f32x4*)gp, g1v = *(const f32x4*)(gp+4);
  f32x4 b0 = *(const f32x4*)bp, b1v = *(const f32x4*)(bp+4);
  f32x4 o0, o1;
  o0.x=(u.x-mu)*rstd*g0.x+b0.x;  o0.y=(u.y-mu)*rstd*g0.y+b0.y;
  o0.z=(u.z-mu)*rstd*g0.z+b0.z;  o0.w=(u.w-mu)*rstd*g0.w+b0.w;
  o1.x=(v.x-mu)*rstd*g1v.x+b1v.x; o1.y=(v.y-mu)*rstd*g1v.y+b1v.y;
  o1.z=(v.z-mu)*rstd*g1v.z+b1v.z; o1.w=(v.w-mu)*rstd*g1v.w+b1v.w;
  float* xp = X + (size_t)row * 512 + lane * 8;
  *(f32x4*)xp       = o0;
  *(f32x4*)(xp + 4) = o1;
  u32x4 w;
  w[0]=pack2(o0.x,o0.y); w[1]=pack2(o0.z,o0.w); w[2]=pack2(o1.x,o1.y); w[3]=pack2(o1.z,o1.w);
  *(u32x4*)(Xb + (size_t)row * 512 + lane * 8) = w;
}

// ---------------------------------------------------------------------------
// Decoder helpers
// ---------------------------------------------------------------------------
// Build B-frags for matvec y = W@x: x occupies column 0 of B.
__device__ __forceinline__ void make_vec_bfrag(const float* __restrict__ x,
                                               int lane, bf16x8 bf[4]){
  const int kg = lane >> 4;
  const bool act = (lane & 15) == 0;
  bf16x8 z8 = {0,0,0,0,0,0,0,0};
  #pragma unroll
  for (int kb = 0; kb < 4; ++kb){
    f32x4 u = *(const f32x4*)(x + kb*32 + kg*8);
    f32x4 v = *(const f32x4*)(x + kb*32 + kg*8 + 4);
    bf16x8 r = pack8(u, v);
    bf[kb] = act ? r : z8;
  }
}

// ---------------------------------------------------------------------------
// Decoder v3: 8 waves per batch; weights in registers; phases split by wave.
// ---------------------------------------------------------------------------
__global__ void __launch_bounds__(512) decode_kernel(
    const ushort_t* __restrict__ MEMb,        // [32*64][128] bf16
    const ushort_t* __restrict__ Wsaqkv,      // [384][128] bf16
    const ushort_t* __restrict__ Wsaout,      // [128][128]
    const ushort_t* __restrict__ Wcaqkv,      // [384][128]: rows 0-127 q, 128-383 kv
    const ushort_t* __restrict__ Wcaout,      // [128][128]
    const ushort_t* __restrict__ Wff1,        // [16][128]
    const ushort_t* __restrict__ Wff2,        // [128][16] (+pad)
    const float* __restrict__ saqkv_b, const float* __restrict__ saout_b,
    const float* __restrict__ caqkv_b, const float* __restrict__ caout_b,
    const float* __restrict__ f1b, const float* __restrict__ f2b,
    const float* __restrict__ g1, const float* __restrict__ b1,
    const float* __restrict__ g2, const float* __restrict__ b2,
    const float* __restrict__ g3, const float* __restrict__ b3,
    float* __restrict__ Out)
{
  __shared__ __attribute__((aligned(16))) ushort_t Ksa[64*KC_STRIDE];
  __shared__ __attribute__((aligned(16))) ushort_t VsaT[128*VT_STRIDE];
  __shared__ __attribute__((aligned(16))) ushort_t Kc [64*KC_STRIDE];
  __shared__ __attribute__((aligned(16))) ushort_t VcT[128*VT_STRIDE];
  __shared__ __attribute__((aligned(16))) float scores[8*SC_STRIDE];
  __shared__ __attribute__((aligned(16))) float pbuf[8*SC_STRIDE];
  __shared__ __attribute__((aligned(16))) float xcur[128], x1[128], x2[128];
  __shared__ __attribute__((aligned(16))) float qbuf[128], obuf[128], rtmp[128];
  __shared__ __attribute__((aligned(16))) float hbuf[32];
  __shared__ __attribute__((aligned(16))) float bsaq[384];
  __shared__ __attribute__((aligned(16))) float bsao[128], bcaq[128], bcakv[256], bcao[128];
  __shared__ __attribute__((aligned(16))) float bff1[16], bff2[128];
  __shared__ __attribute__((aligned(16))) float lg1[128], lb1[128], lg2[128], lb2[128], lg3[128], lb3[128];

  const int tid  = threadIdx.x;
  const int lane = tid & 63;
  const int wid  = tid >> 6;          // 0..7
  const int col = lane & 15, kg = lane >> 4;
  const int b = blockIdx.x;
  f32x4 z4 = {0.f,0.f,0.f,0.f};
  bf16x8 z8 = {0,0,0,0,0,0,0,0};

  // --- preamble: params + zero-init (512 threads) ---
  if (tid < 384) bsaq[tid] = saqkv_b[tid];
  if (tid < 256) bcakv[tid] = caqkv_b[128 + tid];
  if (tid < 128){
    bsao[tid] = saout_b[tid]; bcaq[tid] = caqkv_b[tid]; bcao[tid] = caout_b[tid]; bff2[tid] = f2b[tid];
    lg1[tid]=g1[tid]; lb1[tid]=b1[tid]; lg2[tid]=g2[tid]; lb2[tid]=b2[tid]; lg3[tid]=g3[tid]; lb3[tid]=b3[tid];
    xcur[tid] = 0.f;   // tgt row 0 is zero
  }
  if (tid < 16) bff1[tid] = f1b[tid];
  if (tid < 32) hbuf[tid] = 0.f;   // pad [16..31] stays 0 forever
  for (int i = tid; i < 128*VT_STRIDE; i += 512) VsaT[i] = 0;  // p=0*NaN hazard

  // --- preamble: load this wave's weight fragments into registers ---
  // A-frag layout: row = rt*16 + col, k = kb*32 + kg*8 + i
  bf16x8 wsaq[3][4];   // SA qkv rows: rt = wid*3 + r  (24 rt total)
  #pragma unroll
  for (int r = 0; r < 3; ++r)
    #pragma unroll
    for (int kb = 0; kb < 4; ++kb)
      wsaq[r][kb] = *(const bf16x8*)(Wsaqkv + ((wid*3 + r)*16 + col)*128 + kb*32 + kg*8);
  bf16x8 wsao[4], wcaqr[4], wcaor[4], wf1[4];
  #pragma unroll
  for (int kb = 0; kb < 4; ++kb){
    wsao[kb]  = *(const bf16x8*)(Wsaout + (wid*16 + col)*128 + kb*32 + kg*8);
    wcaqr[kb] = *(const bf16x8*)(Wcaqkv + (wid*16 + col)*128 + kb*32 + kg*8);
    wcaor[kb] = *(const bf16x8*)(Wcaout + (wid*16 + col)*128 + kb*32 + kg*8);
    wf1[kb]   = *(const bf16x8*)(Wff1 + col*128 + kb*32 + kg*8);   // 16 rows total
  }
  bf16x8 wf2 = (kg < 2) ? *(const bf16x8*)(Wff2 + (wid*16 + col)*16 + kg*8) : z8;

  __syncthreads();

  // --- preamble: cross-attn K/V = Wkv @ mem^T (8 waves x 2 rt) ---
  {
    const ushort_t* Wkv = Wcaqkv + 128*128;
    const ushort_t* memb = MEMb + (size_t)b * 64 * 128;
    #pragma unroll
    for (int rr = 0; rr < 2; ++rr){
      int rt = wid*2 + rr;
      #pragma unroll
      for (int jt = 0; jt < 4; ++jt){
        f32x4 acc = z4;
        #pragma unroll
        for (int kb = 0; kb < 4; ++kb){
          bf16x8 a  = *(const bf16x8*)(Wkv  + (rt*16 + col)*128 + kb*32 + kg*8);
          bf16x8 bb = *(const bf16x8*)(memb + (size_t)(jt*16 + col)*128 + kb*32 + kg*8);
          acc = __builtin_amdgcn_mfma_f32_16x16x32_bf16(a, bb, acc, 0,0,0);
        }
        int j  = jt*16 + col;           // D col = mem row
        int r0 = rt*16 + kg*4;          // D rows = W rows
        f32x4 o = acc + *(const f32x4*)(bcakv + r0);
        if (r0 < 128){
          ushort_t* p = Kc + j*KC_STRIDE + r0;
          p[0]=f2bfbits(o.x); p[1]=f2bfbits(o.y); p[2]=f2bfbits(o.z); p[3]=f2bfbits(o.w);
        } else {
          int d = r0 - 128;
          VcT[(d+0)*VT_STRIDE + j] = f2bfbits(o.x);
          VcT[(d+1)*VT_STRIDE + j] = f2bfbits(o.y);
          VcT[(d+2)*VT_STRIDE + j] = f2bfbits(o.z);
          VcT[(d+3)*VT_STRIDE + j] = f2bfbits(o.w);
        }
      }
    }
  }

  for (int t = 0; t < 64; ++t){
    __syncthreads();
    // A: SA qkv — each wave 3 rt. q->qbuf; K->Ksa[t]; V->VsaT[.][t].
    {
      bf16x8 xb[4];
      make_vec_bfrag(xcur, lane, xb);
      #pragma unroll
      for (int r = 0; r < 3; ++r){
        f32x4 acc = z4;
        #pragma unroll
        for (int kb = 0; kb < 4; ++kb)
          acc = __builtin_amdgcn_mfma_f32_16x16x32_bf16(wsaq[r][kb], xb[kb], acc, 0,0,0);
        if (col == 0){
          int r0 = (wid*3 + r)*16 + kg*4;
          f32x4 o = acc + *(const f32x4*)(bsaq + r0);
          if (r0 < 128){
            *(f32x4*)(qbuf + r0) = o;
          } else if (r0 < 256){
            ushort_t* p = Ksa + t*KC_STRIDE + (r0 - 128);
            p[0]=f2bfbits(o.x); p[1]=f2bfbits(o.y); p[2]=f2bfbits(o.z); p[3]=f2bfbits(o.w);
          } else {
            int d = r0 - 256;
            VsaT[(d+0)*VT_STRIDE + t] = f2bfbits(o.x);
            VsaT[(d+1)*VT_STRIDE + t] = f2bfbits(o.y);
            VsaT[(d+2)*VT_STRIDE + t] = f2bfbits(o.z);
            VsaT[(d+3)*VT_STRIDE + t] = f2bfbits(o.w);
          }
        }
      }
    }
    __syncthreads();
    // B: SA scores — waves 0..3, jt = wid. sc[h][j] = 0.25*q[h].K[j][h].
    if (wid < 4){
      const int jt = wid;
      const bool bval = (col == 0 && kg < 2) || (col == 1 && kg >= 2);
      #pragma unroll
      for (int hp = 0; hp < 4; ++hp){
        f32x4 u = *(const f32x4*)(qbuf + hp*32 + kg*8);
        f32x4 v = *(const f32x4*)(qbuf + hp*32 + kg*8 + 4);
        u *= 0.25f; v *= 0.25f;
        bf16x8 qb = pack8(u, v);
        qb = bval ? qb : z8;
        bf16x8 a = *(const bf16x8*)(Ksa + (jt*16 + col)*KC_STRIDE + hp*32 + kg*8);
        f32x4 d = __builtin_amdgcn_mfma_f32_16x16x32_bf16(a, qb, z4, 0,0,0);
        if (col < 2)
          *(f32x4*)(scores + (hp*2 + col)*SC_STRIDE + jt*16 + kg*4) = d;
      }
    }
    __syncthreads();
    // C: SA softmax (wave 0) — j=0 zero-row with multiplicity (65-t), j<=t valid.
    if (wid == 0){
      const int h = lane >> 3, jj = lane & 7;
      float sv[8];
      *(f32x4*)(sv)     = *(const f32x4*)(scores + h*SC_STRIDE + jj*8);
      *(f32x4*)(sv + 4) = *(const f32x4*)(scores + h*SC_STRIDE + jj*8 + 4);
      #pragma unroll
      for (int i = 0; i < 8; ++i){ int j = jj*8 + i; sv[i] = (j <= t) ? sv[i] : -1e30f; }
      float mx = sv[0];
      #pragma unroll
      for (int i = 1; i < 8; ++i) mx = fmaxf(mx, sv[i]);
      mx = fmaxf(mx, __shfl_xor(mx, 1));
      mx = fmaxf(mx, __shfl_xor(mx, 2));
      mx = fmaxf(mx, __shfl_xor(mx, 4));
      float e[8];
      #pragma unroll
      for (int i = 0; i < 8; ++i) e[i] = __expf(sv[i] - mx);
      if (jj == 0) e[0] *= (float)(65 - t);
      float sum = 0.f;
      #pragma unroll
      for (int i = 0; i < 8; ++i) sum += e[i];
      sum += __shfl_xor(sum, 1);
      sum += __shfl_xor(sum, 2);
      sum += __shfl_xor(sum, 4);
      float inv = 1.f / sum;
      f32x4 p0 = {e[0]*inv, e[1]*inv, e[2]*inv, e[3]*inv};
      f32x4 p1 = {e[4]*inv, e[5]*inv, e[6]*inv, e[7]*inv};
      *(f32x4*)(pbuf + h*SC_STRIDE + jj*8)     = p0;
      *(f32x4*)(pbuf + h*SC_STRIDE + jj*8 + 4) = p1;
    }
    __syncthreads();
    // D: SA weighted V — wave w handles head h = wid. o[d]=sum_j p[h][j]*VT[d][j].
    {
      const int h = wid;
      f32x4 acc = z4;
      #pragma unroll
      for (int jb = 0; jb < 2; ++jb){
        f32x4 u = *(const f32x4*)(pbuf + h*SC_STRIDE + jb*32 + kg*8);
        f32x4 v = *(const f32x4*)(pbuf + h*SC_STRIDE + jb*32 + kg*8 + 4);
        bf16x8 pb = pack8(u, v);
        pb = (col == 0) ? pb : z8;
        bf16x8 a = *(const bf16x8*)(VsaT + (h*16 + col)*VT_STRIDE + jb*32 + kg*8);
        acc = __builtin_amdgcn_mfma_f32_16x16x32_bf16(a, pb, acc, 0,0,0);
      }
      if (col == 0)
        *(f32x4*)(obuf + h*16 + kg*4) = acc;
    }
    __syncthreads();
    // E: SA out-proj — wave w: rt = wid. rtmp = W@obuf + bias.
    {
      bf16x8 xb[4];
      make_vec_bfrag(obuf, lane, xb);
      f32x4 acc = z4;
      #pragma unroll
      for (int kb = 0; kb < 4; ++kb)
        acc = __builtin_amdgcn_mfma_f32_16x16x32_bf16(wsao[kb], xb[kb], acc, 0,0,0);
      if (col == 0){
        int r0 = wid*16 + kg*4;
        *(f32x4*)(rtmp + r0) = acc + *(const f32x4*)(bsao + r0);
      }
    }
    __syncthreads();
    // F: LN1 (wave 0): x1 = LN(rtmp + xcur)
    if (wid == 0){
      float a0 = rtmp[lane] + xcur[lane];
      float a1 = rtmp[lane+64] + xcur[lane+64];
      float s = a0 + a1, sq = a0*a0 + a1*a1;
      #pragma unroll
      for (int off = 1; off < 64; off <<= 1){ s += __shfl_xor(s, off); sq += __shfl_xor(sq, off); }
      float mu = s*(1.f/128.f), var = sq*(1.f/128.f) - mu*mu;
      float rs = rsqrtf(var + LN_EPS);
      x1[lane]    = (a0-mu)*rs*lg1[lane]    + lb1[lane];
      x1[lane+64] = (a1-mu)*rs*lg1[lane+64] + lb1[lane+64];
    }
    __syncthreads();
    // G: CA q — wave w: rt = wid.
    {
      bf16x8 xb[4];
      make_vec_bfrag(x1, lane, xb);
      f32x4 acc = z4;
      #pragma unroll
      for (int kb = 0; kb < 4; ++kb)
        acc = __builtin_amdgcn_mfma_f32_16x16x32_bf16(wcaqr[kb], xb[kb], acc, 0,0,0);
      if (col == 0){
        int r0 = wid*16 + kg*4;
        *(f32x4*)(qbuf + r0) = acc + *(const f32x4*)(bcaq + r0);
      }
    }
    __syncthreads();
    // H: CA scores — waves 0..3, jt = wid, on Kc.
    if (wid < 4){
      const int jt = wid;
      const bool bval = (col == 0 && kg < 2) || (col == 1 && kg >= 2);
      #pragma unroll
      for (int hp = 0; hp < 4; ++hp){
        f32x4 u = *(const f32x4*)(qbuf + hp*32 + kg*8);
        f32x4 v = *(const f32x4*)(qbuf + hp*32 + kg*8 + 4);
        u *= 0.25f; v *= 0.25f;
        bf16x8 qb = pack8(u, v);
        qb = bval ? qb : z8;
        bf16x8 a = *(const bf16x8*)(Kc + (jt*16 + col)*KC_STRIDE + hp*32 + kg*8);
        f32x4 d = __builtin_amdgcn_mfma_f32_16x16x32_bf16(a, qb, z4, 0,0,0);
        if (col < 2)
          *(f32x4*)(scores + (hp*2 + col)*SC_STRIDE + jt*16 + kg*4) = d;
      }
    }
    __syncthreads();
    // I: CA softmax (wave 0), all 64 valid.
    if (wid == 0){
      const int h = lane >> 3, jj = lane & 7;
      float sv[8];
      *(f32x4*)(sv)     = *(const f32x4*)(scores + h*SC_STRIDE + jj*8);
      *(f32x4*)(sv + 4) = *(const f32x4*)(scores + h*SC_STRIDE + jj*8 + 4);
      float mx = sv[0];
      #pragma unroll
      for (int i = 1; i < 8; ++i) mx = fmaxf(mx, sv[i]);
      mx = fmaxf(mx, __shfl_xor(mx, 1));
      mx = fmaxf(mx, __shfl_xor(mx, 2));
      mx = fmaxf(mx, __shfl_xor(mx, 4));
      float e[8], sum = 0.f;
      #pragma unroll
      for (int i = 0; i < 8; ++i){ e[i] = __expf(sv[i] - mx); sum += e[i]; }
      sum += __shfl_xor(sum, 1);
      sum += __shfl_xor(sum, 2);
      sum += __shfl_xor(sum, 4);
      float inv = 1.f / sum;
      f32x4 p0 = {e[0]*inv, e[1]*inv, e[2]*inv, e[3]*inv};
      f32x4 p1 = {e[4]*inv, e[5]*inv, e[6]*inv, e[7]*inv};
      *(f32x4*)(pbuf + h*SC_STRIDE + jj*8)     = p0;
      *(f32x4*)(pbuf + h*SC_STRIDE + jj*8 + 4) = p1;
    }
    __syncthreads();
    // J: CA weighted V — wave w: h = wid, on VcT.
    {
      const int h = wid;
      f32x4 acc = z4;
      #pragma unroll
      for (int jb = 0; jb < 2; ++jb){
        f32x4 u = *(const f32x4*)(pbuf + h*SC_STRIDE + jb*32 + kg*8);
        f32x4 v = *(const f32x4*)(pbuf + h*SC_STRIDE + jb*32 + kg*8 + 4);
        bf16x8 pb = pack8(u, v);
        pb = (col == 0) ? pb : z8;
        bf16x8 a = *(const bf16x8*)(VcT + (h*16 + col)*VT_STRIDE + jb*32 + kg*8);
        acc = __builtin_amdgcn_mfma_f32_16x16x32_bf16(a, pb, acc, 0,0,0);
      }
      if (col == 0)
        *(f32x4*)(obuf + h*16 + kg*4) = acc;
    }
    __syncthreads();
    // K: CA out-proj — wave w: rt = wid.
    {
      bf16x8 xb[4];
      make_vec_bfrag(obuf, lane, xb);
      f32x4 acc = z4;
      #pragma unroll
      for (int kb = 0; kb < 4; ++kb)
        acc = __builtin_amdgcn_mfma_f32_16x16x32_bf16(wcaor[kb], xb[kb], acc, 0,0,0);
      if (col == 0){
        int r0 = wid*16 + kg*4;
        *(f32x4*)(rtmp + r0) = acc + *(const f32x4*)(bcao + r0);
      }
    }
    __syncthreads();
    // L: LN2 (wave 0): x2 = LN(rtmp + x1)
    if (wid == 0){
      float a0 = rtmp[lane] + x1[lane];
      float a1 = rtmp[lane+64] + x1[lane+64];
      float s = a0 + a1, sq = a0*a0 + a1*a1;
      #pragma unroll
      for (int off = 1; off < 64; off <<= 1){ s += __shfl_xor(s, off); sq += __shfl_xor(sq, off); }
      float mu = s*(1.f/128.f), var = sq*(1.f/128.f) - mu*mu;
      float rs = rsqrtf(var + LN_EPS);
      x2[lane]    = (a0-mu)*rs*lg2[lane]    + lb2[lane];
      x2[lane+64] = (a1-mu)*rs*lg2[lane+64] + lb2[lane+64];
    }
    __syncthreads();
    // M: FF1 (wave 7, single rt) -> hbuf with relu.
    if (wid == 7){
      bf16x8 xb[4];
      make_vec_bfrag(x2, lane, xb);
      f32x4 acc = z4;
      #pragma unroll
      for (int kb = 0; kb < 4; ++kb)
        acc = __builtin_amdgcn_mfma_f32_16x16x32_bf16(wf1[kb], xb[kb], acc, 0,0,0);
      if (col == 0){
        int r0 = kg*4;
        f32x4 o = acc + *(const f32x4*)(bff1 + r0);
        hbuf[r0+0]=fmaxf(o.x,0.f); hbuf[r0+1]=fmaxf(o.y,0.f);
        hbuf[r0+2]=fmaxf(o.z,0.f); hbuf[r0+3]=fmaxf(o.w,0.f);
      }
    }
    __syncthreads();
    // N: FF2 — wave w: rt = wid (K=16 padded to 32; hbuf[16..31]=0, wf2 kg>=2 zero).
    {
      f32x4 u = *(const f32x4*)(hbuf + kg*8);
      f32x4 v = *(const f32x4*)(hbuf + kg*8 + 4);
      bf16x8 hb = pack8(u, v);
      hb = (col == 0) ? hb : z8;
      f32x4 acc = __builtin_amdgcn_mfma_f32_16x16x32_bf16(wf2, hb, z4, 0,0,0);
      if (col == 0){
        int r0 = wid*16 + kg*4;
        *(f32x4*)(rtmp + r0) = acc + *(const f32x4*)(bff2 + r0);
      }
    }
    __syncthreads();
    // O: LN3 (wave 0): xcur = LN(rtmp + x2); write Out row t.
    if (wid == 0){
      float a0 = rtmp[lane] + x2[lane];
      float a1 = rtmp[lane+64] + x2[lane+64];
      float s = a0 + a1, sq = a0*a0 + a1*a1;
      #pragma unroll
      for (int off = 1; off < 64; off <<= 1){ s += __shfl_xor(s, off); sq += __shfl_xor(sq, off); }
      float mu = s*(1.f/128.f), var = sq*(1.f/128.f) - mu*mu;
      float rs = rsqrtf(var + LN_EPS);
      float o0 = (a0-mu)*rs*lg3[lane]    + lb3[lane];
      float o1 = (a1-mu)*rs*lg3[lane+64] + lb3[lane+64];
      xcur[lane]    = o0;
      xcur[lane+64] = o1;
      Out[((size_t)(b*64 + t))*128 + lane]      = o0;
      Out[((size_t)(b*64 + t))*128 + lane + 64] = o1;
    }
  }
}

// ---------------------------------------------------------------------------
extern "C" void kernel_launch(void* const* d_in, const int* in_sizes, int n_in,
                              void* d_out, int out_size, void* d_ws, size_t ws_size,
                              hipStream_t stream)
{
  (void)in_sizes; (void)n_in; (void)out_size; (void)ws_size;
  const float* src   = (const float*)d_in[0];
  const float* eqkvw = (const float*)d_in[1];
  const float* eqkvb = (const float*)d_in[2];
  const float* eow   = (const float*)d_in[3];
  const float* eob   = (const float*)d_in[4];
  const float* ef1w  = (const float*)d_in[5];
  const float* ef1b  = (const float*)d_in[6];
  const float* ef2w  = (const float*)d_in[7];
  const float* ef2b  = (const float*)d_in[8];
  const float* eg1   = (const float*)d_in[9];
  const float* eb1   = (const float*)d_in[10];
  const float* eg2   = (const float*)d_in[11];
  const float* eb2   = (const float*)d_in[12];
  const float* fcw   = (const float*)d_in[13];
  const float* fcb   = (const float*)d_in[14];
  const float* dsaqw = (const float*)d_in[15];
  const float* dsaqb = (const float*)d_in[16];
  const float* dsaow = (const float*)d_in[17];
  const float* dsaob = (const float*)d_in[18];
  const float* dcaqw = (const float*)d_in[19];
  const float* dcaqb = (const float*)d_in[20];
  const float* dcaow = (const float*)d_in[21];
  const float* dcaob = (const float*)d_in[22];
  const float* df1w  = (const float*)d_in[23];
  const float* df1b  = (const float*)d_in[24];
  const float* df2w  = (const float*)d_in[25];
  const float* df2b  = (const float*)d_in[26];
  const float* dg1   = (const float*)d_in[27];
  const float* db1   = (const float*)d_in[28];
  const float* dg2   = (const float*)d_in[29];
  const float* db2   = (const float*)d_in[30];
  const float* dg3   = (const float*)d_in[31];
  const float* db3   = (const float*)d_in[32];

  // ws layout (float offsets). Total 6,195,216 fl = 24.78 MB.
  float* ws = (float*)d_ws;
  ushort_t* QKVb   = (ushort_t*)ws;              // [2048][1536] bf16 (enc, per layer)
  float*    Rb     = ws;                         // [2048][512] f32, overlays dead QKVb
  float*    XA     = ws + 1572864;               // [2048][512] f32
  float*    XB     = ws + 2621440;               // [2048][512] f32
  ushort_t* Xinb   = (ushort_t*)(ws + 3670016);  // [2048][512] bf16 (layer input / fc input)
  ushort_t* Ob     = (ushort_t*)(ws + 4194304);  // [2048][512] bf16 (attn out)
  ushort_t* XBb    = (ushort_t*)(ws + 4718592);  // [2048][512] bf16
  ushort_t* Hb     = (ushort_t*)(ws + 5242880);  // [2048][64] bf16
  ushort_t* MEMbb  = (ushort_t*)(ws + 5308416);  // [2048][128] bf16
  ushort_t* eqkvw_l= (ushort_t*)(ws + 5439488);  // [1536][512] bf16, per-layer
  ushort_t* eow_l  = (ushort_t*)(ws + 5832704);  // [512][512] bf16, per-layer
  ushort_t* ef1w_b = (ushort_t*)(ws + 5963776);  // [4][64][512] bf16 (all layers)
  ushort_t* ef2w_b = (ushort_t*)(ws + 6029312);  // [4][512][64] bf16
  ushort_t* fcw_b  = (ushort_t*)(ws + 6094848);  // [128][512] bf16
  ushort_t* dsaqw_b  = (ushort_t*)(ws + 6127616);
  ushort_t* dsaow_b  = (ushort_t*)(ws + 6152192);
  ushort_t* dcaqkv_b = (ushort_t*)(ws + 6160384);
  ushort_t* dcaow_b  = (ushort_t*)(ws + 6184960);
  ushort_t* df1w_b   = (ushort_t*)(ws + 6193152);
  ushort_t* df2w_b   = (ushort_t*)(ws + 6194176); // 2048 + 32 pad

  // prolog: batched f32->bf16 conversions (src + all layer-invariant weights)
  cvt10<<<dim3(512,10),256,0,stream>>>(
      src,   Xinb,    1048576,
      ef1w,  ef1w_b,  131072,
      ef2w,  ef2w_b,  131072,
      fcw,   fcw_b,   65536,
      dsaqw, dsaqw_b, 49152,
      dsaow, dsaow_b, 16384,
      dcaqw, dcaqkv_b,49152,
      dcaow, dcaow_b, 16384,
      df1w,  df1w_b,  2048,
      df2w,  df2w_b,  2048);

  const float* Xres = src;
  for (int l = 0; l < 4; ++l){
    cvt10<<<dim3(384,2),256,0,stream>>>(
        eqkvw + (size_t)l*786432, eqkvw_l, 786432,
        eow   + (size_t)l*262144, eow_l,   262144,
        nullptr,nullptr,0, nullptr,nullptr,0, nullptr,nullptr,0,
        nullptr,nullptr,0, nullptr,nullptr,0, nullptr,nullptr,0,
        nullptr,nullptr,0, nullptr,nullptr,0);
    gemm_bf16<<<dim3(32,24),256,0,stream>>>(Xinb, eqkvw_l, eqkvb + l*1536, nullptr,
                                            nullptr, QKVb, 2048, 1536, 512, 0);
    enc_attn_kernel<<<dim3(32,8),256,0,stream>>>(QKVb, Ob);
    gemm_bf16<<<dim3(32,8),256,0,stream>>>(Ob, eow_l, eob + l*512, Xres,
                                           Rb, nullptr, 2048, 512, 512, 0);
    ln512_kernel<<<dim3(512),256,0,stream>>>(Rb, eg1 + l*512, eb1 + l*512, XB, XBb);
    gemm_bf16<<<dim3(32,1),256,0,stream>>>(XBb, ef1w_b + (size_t)l*32768, ef1b + l*64,
                                           nullptr, nullptr, Hb, 2048, 64, 512, 1);
    gemm_bf16<<<dim3(32,8),256,0,stream>>>(Hb, ef2w_b + (size_t)l*32768, ef2b + l*512,
                                           XB, Rb, nullptr, 2048, 512, 64, 0);
    ln512_kernel<<<dim3(512),256,0,stream>>>(Rb, eg2 + l*512, eb2 + l*512, XA, Xinb);
    Xres = XA;
  }
  gemm_bf16<<<dim3(32,2),256,0,stream>>>(Xinb, fcw_b, fcb, nullptr,
                                         nullptr, MEMbb, 2048, 128, 512, 0);
  decode_kernel<<<dim3(32),512,0,stream>>>(MEMbb,
      dsaqw_b, dsaow_b, dcaqkv_b, dcaow_b, df1w_b, df2w_b,
      dsaqb, dsaob, dcaqb, dcaob, df1b, df2b,
      dg1, db1, dg2, db2, dg3, db3, (float*)d_out);
}

// Round 12
// 834.744 us; speedup vs baseline: 2.5380x; 1.0085x over previous
//
#include <hip/hip_runtime.h>
#include <hip/hip_bf16.h>

// CustomTransformer. Encoder: per layer only 4 kernels (qkv GEMM, attn,
// oproj+LN1 fused, ff1+ff2+LN2 fused); one batched cvt prolog. Decoder: 8
// waves/batch, weights in registers, MFMA everywhere (unchanged from r11).

typedef __attribute__((ext_vector_type(8))) short bf16x8;
typedef __attribute__((ext_vector_type(4))) float f32x4;
typedef __attribute__((ext_vector_type(4))) unsigned int u32x4;
typedef unsigned short ushort_t;
typedef unsigned int uint_t;

#define LN_EPS 1e-5f
#define KC_STRIDE 136
#define VT_STRIDE 72
#define SC_STRIDE 72

__device__ __forceinline__ ushort_t f2bfbits(float f){
  union { __hip_bfloat16 h; ushort_t u; } cv;
  cv.h = __float2bfloat16(f);   // RNE
  return cv.u;
}
__device__ __forceinline__ uint_t pack2(float a, float b){
  return (uint_t)f2bfbits(a) | ((uint_t)f2bfbits(b) << 16);
}
__device__ __forceinline__ bf16x8 pack8(f32x4 u, f32x4 v){
  bf16x8 r;
  r[0]=(short)f2bfbits(u.x); r[1]=(short)f2bfbits(u.y);
  r[2]=(short)f2bfbits(u.z); r[3]=(short)f2bfbits(u.w);
  r[4]=(short)f2bfbits(v.x); r[5]=(short)f2bfbits(v.y);
  r[6]=(short)f2bfbits(v.z); r[7]=(short)f2bfbits(v.w);
  return r;
}

// ---------------------------------------------------------------------------
// Batched f32 -> bf16 conversion (12 tensors, blockIdx.y selects; n=0 skips)
// ---------------------------------------------------------------------------
__global__ void __launch_bounds__(256) cvt12(
    const float* s0, ushort_t* d0, int n0,  const float* s1, ushort_t* d1, int n1,
    const float* s2, ushort_t* d2, int n2,  const float* s3, ushort_t* d3, int n3,
    const float* s4, ushort_t* d4, int n4,  const float* s5, ushort_t* d5, int n5,
    const float* s6, ushort_t* d6, int n6,  const float* s7, ushort_t* d7, int n7,
    const float* s8, ushort_t* d8, int n8,  const float* s9, ushort_t* d9, int n9,
    const float* sa, ushort_t* da, int na,  const float* sb, ushort_t* db, int nb)
{
  const float* s; ushort_t* d; int n;
  switch (blockIdx.y){
    case 0:  s=s0; d=d0; n=n0; break;
    case 1:  s=s1; d=d1; n=n1; break;
    case 2:  s=s2; d=d2; n=n2; break;
    case 3:  s=s3; d=d3; n=n3; break;
    case 4:  s=s4; d=d4; n=n4; break;
    case 5:  s=s5; d=d5; n=n5; break;
    case 6:  s=s6; d=d6; n=n6; break;
    case 7:  s=s7; d=d7; n=n7; break;
    case 8:  s=s8; d=d8; n=n8; break;
    case 9:  s=s9; d=d9; n=n9; break;
    case 10: s=sa; d=da; n=na; break;
    default: s=sb; d=db; n=nb; break;
  }
  for (int i = (blockIdx.x*256 + threadIdx.x)*8; i < n; i += gridDim.x*256*8){
    f32x4 u = *(const f32x4*)(s + i);
    f32x4 v = *(const f32x4*)(s + i + 4);
    u32x4 w;
    w[0]=pack2(u.x,u.y); w[1]=pack2(u.z,u.w); w[2]=pack2(v.x,v.y); w[3]=pack2(v.z,v.w);
    *(u32x4*)(d + i) = w;
  }
}

// ---------------------------------------------------------------------------
// Generic bf16 GEMM (used for qkv and fc): C=f32 and/or Cb=bf16 outputs.
// ---------------------------------------------------------------------------
__global__ void __launch_bounds__(256) gemm_bf16(
    const ushort_t* __restrict__ A, const ushort_t* __restrict__ W,
    const float* __restrict__ bias, const float* __restrict__ resid,
    float* __restrict__ C, ushort_t* __restrict__ Cb,
    int M, int N, int K, int relu)
{
  const int tid  = threadIdx.x;
  const int lane = tid & 63;
  const int wid  = tid >> 6;
  const int rowBase = blockIdx.x * 64 + (wid >> 1) * 32;
  const int colBase = blockIdx.y * 64 + (wid & 1) * 32;
  const int r16 = lane & 15;
  const int kg  = lane >> 4;

  f32x4 zz = {0.f,0.f,0.f,0.f};
  f32x4 acc[2][2];
  acc[0][0]=zz; acc[0][1]=zz; acc[1][0]=zz; acc[1][1]=zz;

  const ushort_t* Ap = A + (size_t)(rowBase + r16) * K + kg*8;
  const ushort_t* Wp = W + (size_t)(colBase + r16) * K + kg*8;
  #pragma unroll 4
  for (int k0 = 0; k0 < K; k0 += 32){
    bf16x8 af0 = *(const bf16x8*)(Ap + k0);
    bf16x8 af1 = *(const bf16x8*)(Ap + (size_t)16*K + k0);
    bf16x8 bf0 = *(const bf16x8*)(Wp + k0);
    bf16x8 bf1 = *(const bf16x8*)(Wp + (size_t)16*K + k0);
    acc[0][0] = __builtin_amdgcn_mfma_f32_16x16x32_bf16(af0, bf0, acc[0][0], 0,0,0);
    acc[0][1] = __builtin_amdgcn_mfma_f32_16x16x32_bf16(af0, bf1, acc[0][1], 0,0,0);
    acc[1][0] = __builtin_amdgcn_mfma_f32_16x16x32_bf16(af1, bf0, acc[1][0], 0,0,0);
    acc[1][1] = __builtin_amdgcn_mfma_f32_16x16x32_bf16(af1, bf1, acc[1][1], 0,0,0);
  }

  #pragma unroll
  for (int mt = 0; mt < 2; ++mt)
  #pragma unroll
  for (int nt = 0; nt < 2; ++nt)
  #pragma unroll
  for (int i = 0; i < 4; ++i){
    int row = rowBase + mt*16 + kg*4 + i;   // C/D: row=(lane>>4)*4+i
    int col = colBase + nt*16 + r16;        //      col=lane&15
    float v = acc[mt][nt][i] + bias[col];
    if (resid) v += resid[(size_t)row * N + col];
    if (relu)  v = fmaxf(v, 0.f);
    if (C)  C[(size_t)row * N + col] = v;
    if (Cb) Cb[(size_t)row * N + col] = f2bfbits(v);
  }
}

// ---------------------------------------------------------------------------
// Encoder attention: one block per (batch, head). dh=64, S=64, scale=1/8.
// ---------------------------------------------------------------------------
#define APAD 68
__global__ void __launch_bounds__(256) enc_attn_kernel(
    const ushort_t* __restrict__ QKVb, ushort_t* __restrict__ Ob)
{
  __shared__ __attribute__((aligned(16))) float Qs[64][APAD];
  __shared__ __attribute__((aligned(16))) float Ks[64][APAD];
  __shared__ __attribute__((aligned(16))) float Vs[64][APAD];
  __shared__ __attribute__((aligned(16))) float Ss[64][APAD];
  const int b = blockIdx.x, h = blockIdx.y;
  const int tid = threadIdx.x;
  const ushort_t* base = QKVb + (size_t)b * 64 * 1536 + h * 64;
  for (int idx = tid; idx < 1536; idx += 256){
    int a = idx >> 9, rem = idx & 511;
    int tt = rem >> 3, c8 = (rem & 7) * 8;
    u32x4 w = *(const u32x4*)(base + (size_t)tt * 1536 + a * 512 + c8);
    float* dst = (a == 0) ? &Qs[tt][c8] : (a == 1) ? &Ks[tt][c8] : &Vs[tt][c8];
    #pragma unroll
    for (int j2 = 0; j2 < 4; ++j2){
      dst[2*j2]   = __uint_as_float(w[j2] << 16);
      dst[2*j2+1] = __uint_as_float(w[j2] & 0xffff0000u);
    }
  }
  __syncthreads();
  const int r = tid >> 2, cg = tid & 3;
  float qr[64];
  #pragma unroll
  for (int k4 = 0; k4 < 16; ++k4) *(f32x4*)&qr[k4*4] = *(const f32x4*)&Qs[r][k4*4];
  float sv[16];
  #pragma unroll
  for (int i = 0; i < 16; ++i){
    int c = cg * 16 + i;
    float acc = 0.f;
    #pragma unroll
    for (int k4 = 0; k4 < 16; ++k4){
      f32x4 kv = *(const f32x4*)&Ks[c][k4*4];
      acc += qr[k4*4+0]*kv.x + qr[k4*4+1]*kv.y + qr[k4*4+2]*kv.z + qr[k4*4+3]*kv.w;
    }
    sv[i] = acc * 0.125f;
  }
  float mx = -1e30f;
  #pragma unroll
  for (int i = 0; i < 16; ++i) mx = fmaxf(mx, sv[i]);
  mx = fmaxf(mx, __shfl_xor(mx, 1));
  mx = fmaxf(mx, __shfl_xor(mx, 2));
  float sum = 0.f;
  #pragma unroll
  for (int i = 0; i < 16; ++i){ sv[i] = __expf(sv[i] - mx); sum += sv[i]; }
  sum += __shfl_xor(sum, 1);
  sum += __shfl_xor(sum, 2);
  float inv = 1.f / sum;
  #pragma unroll
  for (int i = 0; i < 16; ++i) Ss[r][cg*16 + i] = sv[i] * inv;
  __syncthreads();
  float ar[64];
  #pragma unroll
  for (int k4 = 0; k4 < 16; ++k4) *(f32x4*)&ar[k4*4] = *(const f32x4*)&Ss[r][k4*4];
  f32x4 zz = {0.f,0.f,0.f,0.f};
  f32x4 o4[4]; o4[0]=zz; o4[1]=zz; o4[2]=zz; o4[3]=zz;
  for (int k = 0; k < 64; ++k){
    float s = ar[k];
    #pragma unroll
    for (int q = 0; q < 4; ++q){
      f32x4 v = *(const f32x4*)&Vs[k][cg*16 + q*4];
      o4[q] += v * s;
    }
  }
  ushort_t* op = Ob + ((size_t)(b * 64 + r)) * 512 + h * 64 + cg * 16;
  #pragma unroll
  for (int q = 0; q < 4; ++q){
    op[q*4+0] = f2bfbits(o4[q].x);
    op[q*4+1] = f2bfbits(o4[q].y);
    op[q*4+2] = f2bfbits(o4[q].z);
    op[q*4+3] = f2bfbits(o4[q].w);
  }
}

// ---------------------------------------------------------------------------
// oproj_ln: out-proj (16 rows x 512 cols, K=512) + bias + resid + LayerNorm.
// Block = 256 thr (4 waves x 128 cols). Writes X (f32) + Xb (bf16).
// ---------------------------------------------------------------------------
__global__ void __launch_bounds__(256) oproj_ln(
    const ushort_t* __restrict__ A, const ushort_t* __restrict__ W,
    const float* __restrict__ bias, const float* __restrict__ resid,
    const float* __restrict__ g, const float* __restrict__ bb,
    float* __restrict__ X, ushort_t* __restrict__ Xb)
{
  __shared__ float wsum[4][16], wsq[4][16];
  __shared__ float mu_s[16], rs_s[16];
  const int tid = threadIdx.x, lane = tid & 63, wid = tid >> 6;
  const int c16 = lane & 15, kg = lane >> 4;
  const int rowBase = blockIdx.x * 16;
  f32x4 z4 = {0.f,0.f,0.f,0.f};
  f32x4 acc[8];
  #pragma unroll
  for (int nt = 0; nt < 8; ++nt) acc[nt] = z4;

  const ushort_t* Ap = A + (size_t)(rowBase + c16)*512 + kg*8;
  const ushort_t* Wp = W + (size_t)(wid*128 + c16)*512 + kg*8;
  #pragma unroll 2
  for (int kb = 0; kb < 16; ++kb){
    bf16x8 af = *(const bf16x8*)(Ap + kb*32);
    #pragma unroll
    for (int nt = 0; nt < 8; ++nt){
      bf16x8 wf = *(const bf16x8*)(Wp + (size_t)nt*16*512 + kb*32);
      acc[nt] = __builtin_amdgcn_mfma_f32_16x16x32_bf16(af, wf, acc[nt], 0,0,0);
    }
  }
  // lane holds D rows kg*4+i, cols wid*128+nt*16+c16
  float ps[4] = {0,0,0,0}, pq[4] = {0,0,0,0};
  #pragma unroll
  for (int nt = 0; nt < 8; ++nt){
    int coln = wid*128 + nt*16 + c16;
    float bcol = bias[coln];
    #pragma unroll
    for (int i = 0; i < 4; ++i){
      int row = rowBase + kg*4 + i;
      float v = acc[nt][i] + bcol + resid[(size_t)row*512 + coln];
      acc[nt][i] = v;
      ps[i] += v; pq[i] += v*v;
    }
  }
  #pragma unroll
  for (int off = 1; off < 16; off <<= 1){
    #pragma unroll
    for (int i = 0; i < 4; ++i){
      ps[i] += __shfl_xor(ps[i], off);
      pq[i] += __shfl_xor(pq[i], off);
    }
  }
  if (c16 == 0){
    #pragma unroll
    for (int i = 0; i < 4; ++i){ wsum[wid][kg*4+i] = ps[i]; wsq[wid][kg*4+i] = pq[i]; }
  }
  __syncthreads();
  if (tid < 16){
    float s = wsum[0][tid]+wsum[1][tid]+wsum[2][tid]+wsum[3][tid];
    float q = wsq[0][tid]+wsq[1][tid]+wsq[2][tid]+wsq[3][tid];
    float mu = s * (1.f/512.f);
    float var = q * (1.f/512.f) - mu*mu;
    mu_s[tid] = mu; rs_s[tid] = rsqrtf(var + LN_EPS);
  }
  __syncthreads();
  #pragma unroll
  for (int nt = 0; nt < 8; ++nt){
    int coln = wid*128 + nt*16 + c16;
    float gg = g[coln], b2 = bb[coln];
    #pragma unroll
    for (int i = 0; i < 4; ++i){
      int r = kg*4 + i;
      int row = rowBase + r;
      float o = (acc[nt][i] - mu_s[r]) * rs_s[r] * gg + b2;
      X[(size_t)row*512 + coln] = o;
      Xb[(size_t)row*512 + coln] = f2bfbits(o);
    }
  }
}

// ---------------------------------------------------------------------------
// ff_ln: h = relu(A @ W1^T + b1) [16x64]; out = h @ W2^T + b2 + resid; LN.
// Block = 256 thr; h staged in LDS bf16 (stride 72, conflict-free).
// ---------------------------------------------------------------------------
__global__ void __launch_bounds__(256) ff_ln(
    const ushort_t* __restrict__ A,    // [2048][512] bf16 (XBb)
    const ushort_t* __restrict__ W1,   // [64][512] bf16
    const float* __restrict__ b1v,
    const ushort_t* __restrict__ W2,   // [512][64] bf16
    const float* __restrict__ b2v,
    const float* __restrict__ resid,   // XB f32
    const float* __restrict__ g, const float* __restrict__ bb,
    float* __restrict__ X, ushort_t* __restrict__ Xb)
{
  __shared__ ushort_t hsh[16][72];
  __shared__ float wsum[4][16], wsq[4][16];
  __shared__ float mu_s[16], rs_s[16];
  const int tid = threadIdx.x, lane = tid & 63, wid = tid >> 6;
  const int c16 = lane & 15, kg = lane >> 4;
  const int rowBase = blockIdx.x * 16;
  f32x4 z4 = {0.f,0.f,0.f,0.f};

  // stage 1: hidden tile (wave w -> hidden cols wid*16..+15), K=512
  {
    f32x4 acch = z4;
    const ushort_t* Ap  = A  + (size_t)(rowBase + c16)*512 + kg*8;
    const ushort_t* W1p = W1 + (size_t)(wid*16 + c16)*512 + kg*8;
    #pragma unroll 4
    for (int kb = 0; kb < 16; ++kb){
      bf16x8 af = *(const bf16x8*)(Ap + kb*32);
      bf16x8 wf = *(const bf16x8*)(W1p + kb*32);
      acch = __builtin_amdgcn_mfma_f32_16x16x32_bf16(af, wf, acch, 0,0,0);
    }
    float bc = b1v[wid*16 + c16];
    #pragma unroll
    for (int i = 0; i < 4; ++i)
      hsh[kg*4 + i][wid*16 + c16] = f2bfbits(fmaxf(acch[i] + bc, 0.f));
  }
  __syncthreads();

  // stage 2: out[16][512], K=64 from LDS h
  f32x4 acc[8];
  #pragma unroll
  for (int nt = 0; nt < 8; ++nt) acc[nt] = z4;
  #pragma unroll
  for (int kb = 0; kb < 2; ++kb){
    bf16x8 af = *(const bf16x8*)&hsh[c16][kg*8 + kb*32];
    #pragma unroll
    for (int nt = 0; nt < 8; ++nt){
      bf16x8 wf = *(const bf16x8*)(W2 + (size_t)(wid*128 + nt*16 + c16)*64 + kg*8 + kb*32);
      acc[nt] = __builtin_amdgcn_mfma_f32_16x16x32_bf16(af, wf, acc[nt], 0,0,0);
    }
  }
  // epilogue: + b2 + resid -> LN -> X/Xb
  float ps[4] = {0,0,0,0}, pq[4] = {0,0,0,0};
  #pragma unroll
  for (int nt = 0; nt < 8; ++nt){
    int coln = wid*128 + nt*16 + c16;
    float bcol = b2v[coln];
    #pragma unroll
    for (int i = 0; i < 4; ++i){
      int row = rowBase + kg*4 + i;
      float v = acc[nt][i] + bcol + resid[(size_t)row*512 + coln];
      acc[nt][i] = v;
      ps[i] += v; pq[i] += v*v;
    }
  }
  #pragma unroll
  for (int off = 1; off < 16; off <<= 1){
    #pragma unroll
    for (int i = 0; i < 4; ++i){
      ps[i] += __shfl_xor(ps[i], off);
      pq[i] += __shfl_xor(pq[i], off);
    }
  }
  if (c16 == 0){
    #pragma unroll
    for (int i = 0; i < 4; ++i){ wsum[wid][kg*4+i] = ps[i]; wsq[wid][kg*4+i] = pq[i]; }
  }
  __syncthreads();
  if (tid < 16){
    float s = wsum[0][tid]+wsum[1][tid]+wsum[2][tid]+wsum[3][tid];
    float q = wsq[0][tid]+wsq[1][tid]+wsq[2][tid]+wsq[3][tid];
    float mu = s * (1.f/512.f);
    float var = q * (1.f/512.f) - mu*mu;
    mu_s[tid] = mu; rs_s[tid] = rsqrtf(var + LN_EPS);
  }
  __syncthreads();
  #pragma unroll
  for (int nt = 0; nt < 8; ++nt){
    int coln = wid*128 + nt*16 + c16;
    float gg = g[coln], b2c = bb[coln];
    #pragma unroll
    for (int i = 0; i < 4; ++i){
      int r = kg*4 + i;
      int row = rowBase + r;
      float o = (acc[nt][i] - mu_s[r]) * rs_s[r] * gg + b2c;
      X[(size_t)row*512 + coln] = o;
      Xb[(size_t)row*512 + coln] = f2bfbits(o);
    }
  }
}

// ---------------------------------------------------------------------------
// Decoder helpers (unchanged from round 11)
// ---------------------------------------------------------------------------
__device__ __forceinline__ void make_vec_bfrag(const float* __restrict__ x,
                                               int lane, bf16x8 bf[4]){
  const int kg = lane >> 4;
  const bool act = (lane & 15) == 0;
  bf16x8 z8 = {0,0,0,0,0,0,0,0};
  #pragma unroll
  for (int kb = 0; kb < 4; ++kb){
    f32x4 u = *(const f32x4*)(x + kb*32 + kg*8);
    f32x4 v = *(const f32x4*)(x + kb*32 + kg*8 + 4);
    bf16x8 r = pack8(u, v);
    bf[kb] = act ? r : z8;
  }
}

// ---------------------------------------------------------------------------
// Decoder v3 (unchanged): 8 waves per batch; weights in registers.
// ---------------------------------------------------------------------------
__global__ void __launch_bounds__(512) decode_kernel(
    const ushort_t* __restrict__ MEMb,
    const ushort_t* __restrict__ Wsaqkv, const ushort_t* __restrict__ Wsaout,
    const ushort_t* __restrict__ Wcaqkv, const ushort_t* __restrict__ Wcaout,
    const ushort_t* __restrict__ Wff1, const ushort_t* __restrict__ Wff2,
    const float* __restrict__ saqkv_b, const float* __restrict__ saout_b,
    const float* __restrict__ caqkv_b, const float* __restrict__ caout_b,
    const float* __restrict__ f1b, const float* __restrict__ f2b,
    const float* __restrict__ g1, const float* __restrict__ b1,
    const float* __restrict__ g2, const float* __restrict__ b2,
    const float* __restrict__ g3, const float* __restrict__ b3,
    float* __restrict__ Out)
{
  __shared__ __attribute__((aligned(16))) ushort_t Ksa[64*KC_STRIDE];
  __shared__ __attribute__((aligned(16))) ushort_t VsaT[128*VT_STRIDE];
  __shared__ __attribute__((aligned(16))) ushort_t Kc [64*KC_STRIDE];
  __shared__ __attribute__((aligned(16))) ushort_t VcT[128*VT_STRIDE];
  __shared__ __attribute__((aligned(16))) float scores[8*SC_STRIDE];
  __shared__ __attribute__((aligned(16))) float pbuf[8*SC_STRIDE];
  __shared__ __attribute__((aligned(16))) float xcur[128], x1[128], x2[128];
  __shared__ __attribute__((aligned(16))) float qbuf[128], obuf[128], rtmp[128];
  __shared__ __attribute__((aligned(16))) float hbuf[32];
  __shared__ __attribute__((aligned(16))) float bsaq[384];
  __shared__ __attribute__((aligned(16))) float bsao[128], bcaq[128], bcakv[256], bcao[128];
  __shared__ __attribute__((aligned(16))) float bff1[16], bff2[128];
  __shared__ __attribute__((aligned(16))) float lg1[128], lb1[128], lg2[128], lb2[128], lg3[128], lb3[128];

  const int tid  = threadIdx.x;
  const int lane = tid & 63;
  const int wid  = tid >> 6;          // 0..7
  const int col = lane & 15, kg = lane >> 4;
  const int b = blockIdx.x;
  f32x4 z4 = {0.f,0.f,0.f,0.f};
  bf16x8 z8 = {0,0,0,0,0,0,0,0};

  if (tid < 384) bsaq[tid] = saqkv_b[tid];
  if (tid < 256) bcakv[tid] = caqkv_b[128 + tid];
  if (tid < 128){
    bsao[tid] = saout_b[tid]; bcaq[tid] = caqkv_b[tid]; bcao[tid] = caout_b[tid]; bff2[tid] = f2b[tid];
    lg1[tid]=g1[tid]; lb1[tid]=b1[tid]; lg2[tid]=g2[tid]; lb2[tid]=b2[tid]; lg3[tid]=g3[tid]; lb3[tid]=b3[tid];
    xcur[tid] = 0.f;
  }
  if (tid < 16) bff1[tid] = f1b[tid];
  if (tid < 32) hbuf[tid] = 0.f;
  for (int i = tid; i < 128*VT_STRIDE; i += 512) VsaT[i] = 0;

  bf16x8 wsaq[3][4];
  #pragma unroll
  for (int r = 0; r < 3; ++r)
    #pragma unroll
    for (int kb = 0; kb < 4; ++kb)
      wsaq[r][kb] = *(const bf16x8*)(Wsaqkv + ((wid*3 + r)*16 + col)*128 + kb*32 + kg*8);
  bf16x8 wsao[4], wcaqr[4], wcaor[4], wf1[4];
  #pragma unroll
  for (int kb = 0; kb < 4; ++kb){
    wsao[kb]  = *(const bf16x8*)(Wsaout + (wid*16 + col)*128 + kb*32 + kg*8);
    wcaqr[kb] = *(const bf16x8*)(Wcaqkv + (wid*16 + col)*128 + kb*32 + kg*8);
    wcaor[kb] = *(const bf16x8*)(Wcaout + (wid*16 + col)*128 + kb*32 + kg*8);
    wf1[kb]   = *(const bf16x8*)(Wff1 + col*128 + kb*32 + kg*8);
  }
  bf16x8 wf2 = (kg < 2) ? *(const bf16x8*)(Wff2 + (wid*16 + col)*16 + kg*8) : z8;

  __syncthreads();

  {
    const ushort_t* Wkv = Wcaqkv + 128*128;
    const ushort_t* memb = MEMb + (size_t)b * 64 * 128;
    #pragma unroll
    for (int rr = 0; rr < 2; ++rr){
      int rt = wid*2 + rr;
      #pragma unroll
      for (int jt = 0; jt < 4; ++jt){
        f32x4 acc = z4;
        #pragma unroll
        for (int kb = 0; kb < 4; ++kb){
          bf16x8 a  = *(const bf16x8*)(Wkv  + (rt*16 + col)*128 + kb*32 + kg*8);
          bf16x8 bb = *(const bf16x8*)(memb + (size_t)(jt*16 + col)*128 + kb*32 + kg*8);
          acc = __builtin_amdgcn_mfma_f32_16x16x32_bf16(a, bb, acc, 0,0,0);
        }
        int j  = jt*16 + col;
        int r0 = rt*16 + kg*4;
        f32x4 o = acc + *(const f32x4*)(bcakv + r0);
        if (r0 < 128){
          ushort_t* p = Kc + j*KC_STRIDE + r0;
          p[0]=f2bfbits(o.x); p[1]=f2bfbits(o.y); p[2]=f2bfbits(o.z); p[3]=f2bfbits(o.w);
        } else {
          int d = r0 - 128;
          VcT[(d+0)*VT_STRIDE + j] = f2bfbits(o.x);
          VcT[(d+1)*VT_STRIDE + j] = f2bfbits(o.y);
          VcT[(d+2)*VT_STRIDE + j] = f2bfbits(o.z);
          VcT[(d+3)*VT_STRIDE + j] = f2bfbits(o.w);
        }
      }
    }
  }

  for (int t = 0; t < 64; ++t){
    __syncthreads();
    {
      bf16x8 xb[4];
      make_vec_bfrag(xcur, lane, xb);
      #pragma unroll
      for (int r = 0; r < 3; ++r){
        f32x4 acc = z4;
        #pragma unroll
        for (int kb = 0; kb < 4; ++kb)
          acc = __builtin_amdgcn_mfma_f32_16x16x32_bf16(wsaq[r][kb], xb[kb], acc, 0,0,0);
        if (col == 0){
          int r0 = (wid*3 + r)*16 + kg*4;
          f32x4 o = acc + *(const f32x4*)(bsaq + r0);
          if (r0 < 128){
            *(f32x4*)(qbuf + r0) = o;
          } else if (r0 < 256){
            ushort_t* p = Ksa + t*KC_STRIDE + (r0 - 128);
            p[0]=f2bfbits(o.x); p[1]=f2bfbits(o.y); p[2]=f2bfbits(o.z); p[3]=f2bfbits(o.w);
          } else {
            int d = r0 - 256;
            VsaT[(d+0)*VT_STRIDE + t] = f2bfbits(o.x);
            VsaT[(d+1)*VT_STRIDE + t] = f2bfbits(o.y);
            VsaT[(d+2)*VT_STRIDE + t] = f2bfbits(o.z);
            VsaT[(d+3)*VT_STRIDE + t] = f2bfbits(o.w);
          }
        }
      }
    }
    __syncthreads();
    if (wid < 4){
      const int jt = wid;
      const bool bval = (col == 0 && kg < 2) || (col == 1 && kg >= 2);
      #pragma unroll
      for (int hp = 0; hp < 4; ++hp){
        f32x4 u = *(const f32x4*)(qbuf + hp*32 + kg*8);
        f32x4 v = *(const f32x4*)(qbuf + hp*32 + kg*8 + 4);
        u *= 0.25f; v *= 0.25f;
        bf16x8 qb = pack8(u, v);
        qb = bval ? qb : z8;
        bf16x8 a = *(const bf16x8*)(Ksa + (jt*16 + col)*KC_STRIDE + hp*32 + kg*8);
        f32x4 d = __builtin_amdgcn_mfma_f32_16x16x32_bf16(a, qb, z4, 0,0,0);
        if (col < 2)
          *(f32x4*)(scores + (hp*2 + col)*SC_STRIDE + jt*16 + kg*4) = d;
      }
    }
    __syncthreads();
    if (wid == 0){
      const int h = lane >> 3, jj = lane & 7;
      float sv[8];
      *(f32x4*)(sv)     = *(const f32x4*)(scores + h*SC_STRIDE + jj*8);
      *(f32x4*)(sv + 4) = *(const f32x4*)(scores + h*SC_STRIDE + jj*8 + 4);
      #pragma unroll
      for (int i = 0; i < 8; ++i){ int j = jj*8 + i; sv[i] = (j <= t) ? sv[i] : -1e30f; }
      float mx = sv[0];
      #pragma unroll
      for (int i = 1; i < 8; ++i) mx = fmaxf(mx, sv[i]);
      mx = fmaxf(mx, __shfl_xor(mx, 1));
      mx = fmaxf(mx, __shfl_xor(mx, 2));
      mx = fmaxf(mx, __shfl_xor(mx, 4));
      float e[8];
      #pragma unroll
      for (int i = 0; i < 8; ++i) e[i] = __expf(sv[i] - mx);
      if (jj == 0) e[0] *= (float)(65 - t);
      float sum = 0.f;
      #pragma unroll
      for (int i = 0; i < 8; ++i) sum += e[i];
      sum += __shfl_xor(sum, 1);
      sum += __shfl_xor(sum, 2);
      sum += __shfl_xor(sum, 4);
      float inv = 1.f / sum;
      f32x4 p0 = {e[0]*inv, e[1]*inv, e[2]*inv, e[3]*inv};
      f32x4 p1 = {e[4]*inv, e[5]*inv, e[6]*inv, e[7]*inv};
      *(f32x4*)(pbuf + h*SC_STRIDE + jj*8)     = p0;
      *(f32x4*)(pbuf + h*SC_STRIDE + jj*8 + 4) = p1;
    }
    __syncthreads();
    {
      const int h = wid;
      f32x4 acc = z4;
      #pragma unroll
      for (int jb = 0; jb < 2; ++jb){
        f32x4 u = *(const f32x4*)(pbuf + h*SC_STRIDE + jb*32 + kg*8);
        f32x4 v = *(const f32x4*)(pbuf + h*SC_STRIDE + jb*32 + kg*8 + 4);
        bf16x8 pb = pack8(u, v);
        pb = (col == 0) ? pb : z8;
        bf16x8 a = *(const bf16x8*)(VsaT + (h*16 + col)*VT_STRIDE + jb*32 + kg*8);
        acc = __builtin_amdgcn_mfma_f32_16x16x32_bf16(a, pb, acc, 0,0,0);
      }
      if (col == 0)
        *(f32x4*)(obuf + h*16 + kg*4) = acc;
    }
    __syncthreads();
    {
      bf16x8 xb[4];
      make_vec_bfrag(obuf, lane, xb);
      f32x4 acc = z4;
      #pragma unroll
      for (int kb = 0; kb < 4; ++kb)
        acc = __builtin_amdgcn_mfma_f32_16x16x32_bf16(wsao[kb], xb[kb], acc, 0,0,0);
      if (col == 0){
        int r0 = wid*16 + kg*4;
        *(f32x4*)(rtmp + r0) = acc + *(const f32x4*)(bsao + r0);
      }
    }
    __syncthreads();
    if (wid == 0){
      float a0 = rtmp[lane] + xcur[lane];
      float a1 = rtmp[lane+64] + xcur[lane+64];
      float s = a0 + a1, sq = a0*a0 + a1*a1;
      #pragma unroll
      for (int off = 1; off < 64; off <<= 1){ s += __shfl_xor(s, off); sq += __shfl_xor(sq, off); }
      float mu = s*(1.f/128.f), var = sq*(1.f/128.f) - mu*mu;
      float rs = rsqrtf(var + LN_EPS);
      x1[lane]    = (a0-mu)*rs*lg1[lane]    + lb1[lane];
      x1[lane+64] = (a1-mu)*rs*lg1[lane+64] + lb1[lane+64];
    }
    __syncthreads();
    {
      bf16x8 xb[4];
      make_vec_bfrag(x1, lane, xb);
      f32x4 acc = z4;
      #pragma unroll
      for (int kb = 0; kb < 4; ++kb)
        acc = __builtin_amdgcn_mfma_f32_16x16x32_bf16(wcaqr[kb], xb[kb], acc, 0,0,0);
      if (col == 0){
        int r0 = wid*16 + kg*4;
        *(f32x4*)(qbuf + r0) = acc + *(const f32x4*)(bcaq + r0);
      }
    }
    __syncthreads();
    if (wid < 4){
      const int jt = wid;
      const bool bval = (col == 0 && kg < 2) || (col == 1 && kg >= 2);
      #pragma unroll
      for (int hp = 0; hp < 4; ++hp){
        f32x4 u = *(const f32x4*)(qbuf + hp*32 + kg*8);
        f32x4 v = *(const f32x4*)(qbuf + hp*32 + kg*8 + 4);
        u *= 0.25f; v *= 0.25f;
        bf16x8 qb = pack8(u, v);
        qb = bval ? qb : z8;
        bf16x8 a = *(const bf16x8*)(Kc + (jt*16 + col)*KC_STRIDE + hp*32 + kg*8);
        f32x4 d = __builtin_amdgcn_mfma_f32_16x16x32_bf16(a, qb, z4, 0,0,0);
        if (col < 2)
          *(f32x4*)(scores + (hp*2 + col)*SC_STRIDE + jt*16 + kg*4) = d;
      }
    }
    __syncthreads();
    if (wid == 0){
      const int h = lane >> 3, jj = lane & 7;
      float sv[8];
      *(f32x4*)(sv)     = *(const f32x4*)(scores + h*SC_STRIDE + jj*8);
      *(f32x4*)(sv + 4) = *(const f32x4*)(scores + h*SC_STRIDE + jj*8 + 4);
      float mx = sv[0];
      #pragma unroll
      for (int i = 1; i < 8; ++i) mx = fmaxf(mx, sv[i]);
      mx = fmaxf(mx, __shfl_xor(mx, 1));
      mx = fmaxf(mx, __shfl_xor(mx, 2));
      mx = fmaxf(mx, __shfl_xor(mx, 4));
      float e[8], sum = 0.f;
      #pragma unroll
      for (int i = 0; i < 8; ++i){ e[i] = __expf(sv[i] - mx); sum += e[i]; }
      sum += __shfl_xor(sum, 1);
      sum += __shfl_xor(sum, 2);
      sum += __shfl_xor(sum, 4);
      float inv = 1.f / sum;
      f32x4 p0 = {e[0]*inv, e[1]*inv, e[2]*inv, e[3]*inv};
      f32x4 p1 = {e[4]*inv, e[5]*inv, e[6]*inv, e[7]*inv};
      *(f32x4*)(pbuf + h*SC_STRIDE + jj*8)     = p0;
      *(f32x4*)(pbuf + h*SC_STRIDE + jj*8 + 4) = p1;
    }
    __syncthreads();
    {
      const int h = wid;
      f32x4 acc = z4;
      #pragma unroll
      for (int jb = 0; jb < 2; ++jb){
        f32x4 u = *(const f32x4*)(pbuf + h*SC_STRIDE + jb*32 + kg*8);
        f32x4 v = *(const f32x4*)(pbuf + h*SC_STRIDE + jb*32 + kg*8 + 4);
        bf16x8 pb = pack8(u, v);
        pb = (col == 0) ? pb : z8;
        bf16x8 a = *(const bf16x8*)(VcT + (h*16 + col)*VT_STRIDE + jb*32 + kg*8);
        acc = __builtin_amdgcn_mfma_f32_16x16x32_bf16(a, pb, acc, 0,0,0);
      }
      if (col == 0)
        *(f32x4*)(obuf + h*16 + kg*4) = acc;
    }
    __syncthreads();
    {
      bf16x8 xb[4];
      make_vec_bfrag(obuf, lane, xb);
      f32x4 acc = z4;
      #pragma unroll
      for (int kb = 0; kb < 4; ++kb)
        acc = __builtin_amdgcn_mfma_f32_16x16x32_bf16(wcaor[kb], xb[kb], acc, 0,0,0);
      if (col == 0){
        int r0 = wid*16 + kg*4;
        *(f32x4*)(rtmp + r0) = acc + *(const f32x4*)(bcao + r0);
      }
    }
    __syncthreads();
    if (wid == 0){
      float a0 = rtmp[lane] + x1[lane];
      float a1 = rtmp[lane+64] + x1[lane+64];
      float s = a0 + a1, sq = a0*a0 + a1*a1;
      #pragma unroll
      for (int off = 1; off < 64; off <<= 1){ s += __shfl_xor(s, off); sq += __shfl_xor(sq, off); }
      float mu = s*(1.f/128.f), var = sq*(1.f/128.f) - mu*mu;
      float rs = rsqrtf(var + LN_EPS);
      x2[lane]    = (a0-mu)*rs*lg2[lane]    + lb2[lane];
      x2[lane+64] = (a1-mu)*rs*lg2[lane+64] + lb2[lane+64];
    }
    __syncthreads();
    if (wid == 7){
      bf16x8 xb[4];
      make_vec_bfrag(x2, lane, xb);
      f32x4 acc = z4;
      #pragma unroll
      for (int kb = 0; kb < 4; ++kb)
        acc = __builtin_amdgcn_mfma_f32_16x16x32_bf16(wf1[kb], xb[kb], acc, 0,0,0);
      if (col == 0){
        int r0 = kg*4;
        f32x4 o = acc + *(const f32x4*)(bff1 + r0);
        hbuf[r0+0]=fmaxf(o.x,0.f); hbuf[r0+1]=fmaxf(o.y,0.f);
        hbuf[r0+2]=fmaxf(o.z,0.f); hbuf[r0+3]=fmaxf(o.w,0.f);
      }
    }
    __syncthreads();
    {
      f32x4 u = *(const f32x4*)(hbuf + kg*8);
      f32x4 v = *(const f32x4*)(hbuf + kg*8 + 4);
      bf16x8 hb = pack8(u, v);
      hb = (col == 0) ? hb : z8;
      f32x4 acc = __builtin_amdgcn_mfma_f32_16x16x32_bf16(wf2, hb, z4, 0,0,0);
      if (col == 0){
        int r0 = wid*16 + kg*4;
        *(f32x4*)(rtmp + r0) = acc + *(const f32x4*)(bff2 + r0);
      }
    }
    __syncthreads();
    if (wid == 0){
      float a0 = rtmp[lane] + x2[lane];
      float a1 = rtmp[lane+64] + x2[lane+64];
      float s = a0 + a1, sq = a0*a0 + a1*a1;
      #pragma unroll
      for (int off = 1; off < 64; off <<= 1){ s += __shfl_xor(s, off); sq += __shfl_xor(sq, off); }
      float mu = s*(1.f/128.f), var = sq*(1.f/128.f) - mu*mu;
      float rs = rsqrtf(var + LN_EPS);
      float o0 = (a0-mu)*rs*lg3[lane]    + lb3[lane];
      float o1 = (a1-mu)*rs*lg3[lane+64] + lb3[lane+64];
      xcur[lane]    = o0;
      xcur[lane+64] = o1;
      Out[((size_t)(b*64 + t))*128 + lane]      = o0;
      Out[((size_t)(b*64 + t))*128 + lane + 64] = o1;
    }
  }
}

// ---------------------------------------------------------------------------
extern "C" void kernel_launch(void* const* d_in, const int* in_sizes, int n_in,
                              void* d_out, int out_size, void* d_ws, size_t ws_size,
                              hipStream_t stream)
{
  (void)in_sizes; (void)n_in; (void)out_size;
  const float* src   = (const float*)d_in[0];
  const float* eqkvw = (const float*)d_in[1];
  const float* eqkvb = (const float*)d_in[2];
  const float* eow   = (const float*)d_in[3];
  const float* eob   = (const float*)d_in[4];
  const float* ef1w  = (const float*)d_in[5];
  const float* ef1b  = (const float*)d_in[6];
  const float* ef2w  = (const float*)d_in[7];
  const float* ef2b  = (const float*)d_in[8];
  const float* eg1   = (const float*)d_in[9];
  const float* eb1   = (const float*)d_in[10];
  const float* eg2   = (const float*)d_in[11];
  const float* eb2   = (const float*)d_in[12];
  const float* fcw   = (const float*)d_in[13];
  const float* fcb   = (const float*)d_in[14];
  const float* dsaqw = (const float*)d_in[15];
  const float* dsaqb = (const float*)d_in[16];
  const float* dsaow = (const float*)d_in[17];
  const float* dsaob = (const float*)d_in[18];
  const float* dcaqw = (const float*)d_in[19];
  const float* dcaqb = (const float*)d_in[20];
  const float* dcaow = (const float*)d_in[21];
  const float* dcaob = (const float*)d_in[22];
  const float* df1w  = (const float*)d_in[23];
  const float* df1b  = (const float*)d_in[24];
  const float* df2w  = (const float*)d_in[25];
  const float* df2b  = (const float*)d_in[26];
  const float* dg1   = (const float*)d_in[27];
  const float* db1   = (const float*)d_in[28];
  const float* dg2   = (const float*)d_in[29];
  const float* db2   = (const float*)d_in[30];
  const float* dg3   = (const float*)d_in[31];
  const float* db3   = (const float*)d_in[32];

  // ws layout (float offsets). Common: 5,373,952 fl. Big path adds all-layer
  // eqkv/eow bf16 (total 7,702,560 fl = 30.8 MB); small path keeps per-layer
  // staging (total 6,129,696 fl = 24.5 MB, proven envelope).
  float* ws = (float*)d_ws;
  ushort_t* QKVb   = (ushort_t*)ws;              // [2048][1536] bf16
  float*    XA     = ws + 1572864;               // [2048][512] f32
  float*    XB     = ws + 2621440;               // [2048][512] f32
  ushort_t* Xinb   = (ushort_t*)(ws + 3670016);  // [2048][512] bf16
  ushort_t* Ob     = (ushort_t*)(ws + 4194304);  // [2048][512] bf16
  ushort_t* XBb    = (ushort_t*)(ws + 4718592);  // [2048][512] bf16
  ushort_t* MEMbb  = (ushort_t*)(ws + 5242880);  // [2048][128] bf16 -> 5,373,952

  const bool big = ws_size >= (size_t)7702560 * 4;
  size_t off = 5373952;
  ushort_t* eqkvw_b = (ushort_t*)(ws + off);     // big: [4][1536][512]; small: [1536][512]
  off += big ? 1572864 : 393216;
  ushort_t* eow_b   = (ushort_t*)(ws + off);     // big: [4][512][512]; small: [512][512]
  off += big ? 524288 : 131072;
  ushort_t* ef1w_b  = (ushort_t*)(ws + off); off += 65536;   // [4][64][512]
  ushort_t* ef2w_b  = (ushort_t*)(ws + off); off += 65536;   // [4][512][64]
  ushort_t* fcw_b   = (ushort_t*)(ws + off); off += 32768;   // [128][512]
  ushort_t* dsaqw_b = (ushort_t*)(ws + off); off += 24576;
  ushort_t* dsaow_b = (ushort_t*)(ws + off); off += 8192;
  ushort_t* dcaqkv_b= (ushort_t*)(ws + off); off += 24576;
  ushort_t* dcaow_b = (ushort_t*)(ws + off); off += 8192;
  ushort_t* df1w_b  = (ushort_t*)(ws + off); off += 1024;
  ushort_t* df2w_b  = (ushort_t*)(ws + off); off += 1056;    // 2048 + 32 pad

  // prolog: ONE batched conversion (big path converts everything incl.
  // all-layer eqkv/eow; small path leaves those slots empty).
  cvt12<<<dim3(768,12),256,0,stream>>>(
      src,   Xinb,    1048576,
      big ? eqkvw : nullptr, big ? eqkvw_b : nullptr, big ? 3145728 : 0,
      big ? eow   : nullptr, big ? eow_b   : nullptr, big ? 1048576 : 0,
      ef1w,  ef1w_b,  131072,
      ef2w,  ef2w_b,  131072,
      fcw,   fcw_b,   65536,
      dsaqw, dsaqw_b, 49152,
      dsaow, dsaow_b, 16384,
      dcaqw, dcaqkv_b,49152,
      dcaow, dcaow_b, 16384,
      df1w,  df1w_b,  2048,
      df2w,  df2w_b,  2048);

  const float* Xres = src;
  for (int l = 0; l < 4; ++l){
    const ushort_t* wq;
    const ushort_t* wo;
    if (big){
      wq = eqkvw_b + (size_t)l*786432;
      wo = eow_b   + (size_t)l*262144;
    } else {
      cvt12<<<dim3(768,2),256,0,stream>>>(
          eqkvw + (size_t)l*786432, eqkvw_b, 786432,
          eow   + (size_t)l*262144, eow_b,   262144,
          nullptr,nullptr,0, nullptr,nullptr,0, nullptr,nullptr,0,
          nullptr,nullptr,0, nullptr,nullptr,0, nullptr,nullptr,0,
          nullptr,nullptr,0, nullptr,nullptr,0, nullptr,nullptr,0,
          nullptr,nullptr,0);
      wq = eqkvw_b;
      wo = eow_b;
    }
    gemm_bf16<<<dim3(32,24),256,0,stream>>>(Xinb, wq, eqkvb + l*1536, nullptr,
                                            nullptr, QKVb, 2048, 1536, 512, 0);
    enc_attn_kernel<<<dim3(32,8),256,0,stream>>>(QKVb, Ob);
    oproj_ln<<<dim3(128),256,0,stream>>>(Ob, wo, eob + l*512, Xres,
                                         eg1 + l*512, eb1 + l*512, XB, XBb);
    ff_ln<<<dim3(128),256,0,stream>>>(XBb, ef1w_b + (size_t)l*32768, ef1b + l*64,
                                      ef2w_b + (size_t)l*32768, ef2b + l*512,
                                      XB, eg2 + l*512, eb2 + l*512, XA, Xinb);
    Xres = XA;
  }
  gemm_bf16<<<dim3(32,2),256,0,stream>>>(Xinb, fcw_b, fcb, nullptr,
                                         nullptr, MEMbb, 2048, 128, 512, 0);
  decode_kernel<<<dim3(32),512,0,stream>>>(MEMbb,
      dsaqw_b, dsaow_b, dcaqkv_b, dcaow_b, df1w_b, df2w_b,
      dsaqb, dsaob, dcaqb, dcaob, df1b, df2b,
      dg1, db1, dg2, db2, dg3, db3, (float*)d_out);
}